// Round 4
// baseline (556.363 us; speedup 1.0000x reference)
//
#include <hip/hip_runtime.h>
#include <hip/hip_bf16.h>

#define D_DIM 1024
#define NE 16
#define RK 64
#define NTOK 16384

typedef __bf16 bf16;
typedef __bf16 bf16x8 __attribute__((ext_vector_type(8)));
typedef __bf16 bf16x4 __attribute__((ext_vector_type(4)));
typedef float f32x4 __attribute__((ext_vector_type(4)));

__device__ __forceinline__ void gload16(const void* g, void* l) {
  __builtin_amdgcn_global_load_lds((const __attribute__((address_space(1))) unsigned int*)g,
                                   (__attribute__((address_space(3))) unsigned int*)l,
                                   16, 0, 0);
}

// ---------------- casts (weights only) ----------------
__global__ void k_cast(const float* __restrict__ s, bf16* __restrict__ d, int n4) {
  int i = blockIdx.x * blockDim.x + threadIdx.x;
  if (i >= n4) return;
  float4 v = ((const float4*)s)[i];
  bf16x4 o = { (bf16)v.x, (bf16)v.y, (bf16)v.z, (bf16)v.w };
  ((bf16x4*)d)[i] = o;
}

// ---------------- G = W_gate @ W_enc  (fp64 partial sums, atomic combine) ----------------
// R4: 4 independent fp64 accumulators (dep chain 128 -> 32).
__global__ void k_gmat(const float* __restrict__ Wg, const float* __restrict__ We,
                       float* __restrict__ G) {
  int d = blockIdx.x * 256 + threadIdx.x;
  int e = blockIdx.y;
  int j0 = blockIdx.z * 128;
  double a0 = 0.0, a1 = 0.0, a2 = 0.0, a3 = 0.0;
  for (int j = j0; j < j0 + 128; j += 4) {
    a0 += (double)Wg[e * D_DIM + j + 0] * (double)We[(size_t)(j + 0) * D_DIM + d];
    a1 += (double)Wg[e * D_DIM + j + 1] * (double)We[(size_t)(j + 1) * D_DIM + d];
    a2 += (double)Wg[e * D_DIM + j + 2] * (double)We[(size_t)(j + 2) * D_DIM + d];
    a3 += (double)Wg[e * D_DIM + j + 3] * (double)We[(size_t)(j + 3) * D_DIM + d];
  }
  atomicAdd(&G[e * D_DIM + d], (float)((a0 + a1) + (a2 + a3)));
}

// ---------------- bgate[e] = W_gate[e,:] . b_enc ----------------
__global__ void k_bgate(const float* __restrict__ Wg, const float* __restrict__ be,
                        float* __restrict__ bg) {
  __shared__ double red[256];
  int e = blockIdx.x, t = threadIdx.x;
  double a = 0.0;
  for (int j = t; j < D_DIM; j += 256) a += (double)Wg[e * D_DIM + j] * (double)be[j];
  red[t] = a; __syncthreads();
  for (int s = 128; s > 0; s >>= 1) { if (t < s) red[t] += red[t + s]; __syncthreads(); }
  if (t == 0) bg[e] = (float)red[0];
}

// ---------------- fused gating + x->bf16 cast (R4: no LDS) ----------------
// G (64KB) is L2-resident; read float4 directly from global with full ILP.
// No LDS, no barrier -> occupancy VGPR-limited (~4 waves/SIMD) instead of
// 2 blocks/CU. Per-lane fp32 accumulation order identical to R3 (numerics
// bit-identical).
__global__ __launch_bounds__(256) void k_gatecast(const float* __restrict__ x,
                                                  const float* __restrict__ G,
                                                  const float* __restrict__ bg,
                                                  const float* __restrict__ gamma,
                                                  bf16* __restrict__ xb,
                                                  int* __restrict__ cnt,
                                                  int* __restrict__ lists,
                                                  float* __restrict__ wl) {
  int tid = threadIdx.x;
  int wv = tid >> 6, lane = tid & 63;
  int tokbase = blockIdx.x * 16 + wv * 4;
  const float* xp = x + (size_t)tokbase * D_DIM;
  float acc[4][NE] = {};
#pragma unroll
  for (int it = 0; it < 4; ++it) {
    int d0 = it * 256 + lane * 4;
    float4 xa[4];
#pragma unroll
    for (int t = 0; t < 4; ++t)
      xa[t] = *(const float4*)(xp + t * D_DIM + d0);
#pragma unroll
    for (int t = 0; t < 4; ++t) {
      bf16x4 o = { (bf16)xa[t].x, (bf16)xa[t].y, (bf16)xa[t].z, (bf16)xa[t].w };
      *(bf16x4*)(xb + (size_t)(tokbase + t) * D_DIM + d0) = o;
    }
#pragma unroll
    for (int e = 0; e < NE; ++e) {
      float4 g = *(const float4*)(G + e * D_DIM + d0);
#pragma unroll
      for (int t = 0; t < 4; ++t)
        acc[t][e] += xa[t].x * g.x + xa[t].y * g.y + xa[t].z * g.z + xa[t].w * g.w;
    }
  }
#pragma unroll
  for (int off = 32; off > 0; off >>= 1)
#pragma unroll
    for (int t = 0; t < 4; ++t)
#pragma unroll
      for (int e = 0; e < NE; ++e)
        acc[t][e] += __shfl_xor(acc[t][e], off);

  if (lane < 4) {
    int t = lane;
    int tok = tokbase + t;
    float v1 = -1e30f, v2 = -1e30f; int i1 = 0, i2 = 0;
#pragma unroll
    for (int e = 0; e < NE; ++e) {
      float v = acc[t][e] + bg[e];
      if (v > v1) { v2 = v1; i2 = i1; v1 = v; i1 = e; }
      else if (v > v2) { v2 = v; i2 = e; }
    }
    float e1 = expf(v2 - v1);
    float den = 1.0f + e1 + 1e-12f;
    float w0 = (1.0f / den) * gamma[i1];
    float w1 = (e1 / den) * gamma[i2];
    int p0 = atomicAdd(&cnt[i1], 1);
    lists[(size_t)i1 * NTOK + p0] = tok;
    wl[(size_t)i1 * NTOK + p0] = w0;
    int p1 = atomicAdd(&cnt[NE + i2], 1);
    lists[(size_t)(NE + i2) * NTOK + p1] = tok;
    wl[(size_t)(NE + i2) * NTOK + p1] = w1;
  }
}

// ---------------- encoder GEMM: out = x @ W_enc^T + b (fp32) ; encb = bf16(out) ----------------
__global__ __launch_bounds__(256) void k_encgemm(const bf16* __restrict__ A,
                                                 const bf16* __restrict__ W,
                                                 const float* __restrict__ bias,
                                                 float* __restrict__ out,
                                                 bf16* __restrict__ encb) {
  __shared__ bf16 As[128 * 64];
  __shared__ bf16 Bs[128 * 64];
  const int K = D_DIM;
  int tid = threadIdx.x;
  int bn = blockIdx.x * 128;
  int bm = blockIdx.y * 128;
  int lane = tid & 63, wv = tid >> 6;
  int wm = (wv >> 1) * 64, wn = (wv & 1) * 64;
  int srow = tid >> 3, scol = (tid & 7) * 8;
  int fr = lane & 15, fk = (lane >> 4) * 8;
  f32x4 acc[4][4] = {};
  for (int k0 = 0; k0 < K; k0 += 64) {
    __syncthreads();
#pragma unroll
    for (int p = 0; p < 4; ++p) {
      int r = p * 32 + srow;
      gload16(A + (size_t)(bm + r) * K + k0 + scol, &As[r * 64 + scol]);
    }
#pragma unroll
    for (int p = 0; p < 4; ++p) {
      int r = p * 32 + srow;
      gload16(W + (size_t)(bn + r) * K + k0 + scol, &Bs[r * 64 + scol]);
    }
    __syncthreads();
#pragma unroll
    for (int kk = 0; kk < 2; ++kk) {
      bf16x8 af[4], bv[4];
#pragma unroll
      for (int m = 0; m < 4; ++m)
        af[m] = *(const bf16x8*)&As[(wm + m * 16 + fr) * 64 + kk * 32 + fk];
#pragma unroll
      for (int n = 0; n < 4; ++n)
        bv[n] = *(const bf16x8*)&Bs[(wn + n * 16 + fr) * 64 + kk * 32 + fk];
#pragma unroll
      for (int m = 0; m < 4; ++m)
#pragma unroll
        for (int n = 0; n < 4; ++n)
          acc[m][n] = __builtin_amdgcn_mfma_f32_16x16x32_bf16(af[m], bv[n], acc[m][n], 0, 0, 0);
    }
  }
  int rg = (lane >> 4) * 4;
#pragma unroll
  for (int n = 0; n < 4; ++n) {
    int col = bn + wn + n * 16 + fr;
    float bval = bias[col];
#pragma unroll
    for (int m = 0; m < 4; ++m) {
#pragma unroll
      for (int r = 0; r < 4; ++r) {
        int row = bm + wm + m * 16 + rg + r;
        float v = acc[m][n][r] + bval;
        out[(size_t)row * D_DIM + col] = v;
        encb[(size_t)row * D_DIM + col] = (bf16)v;
      }
    }
  }
}

// ---------------- expert kernel (one slot): gather 64 tokens, S=silu(enc U^T)*coef, out += S V^T ----------------
__global__ __launch_bounds__(256) void k_expert(const bf16* __restrict__ encb,
                                                const bf16* __restrict__ Ub,
                                                const bf16* __restrict__ Vb,
                                                const int* __restrict__ cnt,
                                                const int* __restrict__ lists,
                                                const float* __restrict__ wl,
                                                float* __restrict__ out, int slot) {
  int e = blockIdx.x;
  int c = cnt[slot * NE + e];
  int t0 = blockIdx.y * 64;
  if (t0 >= c) return;
  int nrows = c - t0; if (nrows > 64) nrows = 64;
  const int* tl = lists + (size_t)(slot * NE + e) * NTOK + t0;
  const float* wlp = wl + (size_t)(slot * NE + e) * NTOK + t0;

  __shared__ int toks[64];
  __shared__ float coefs[64];
  __shared__ bf16 As[64 * 64];
  __shared__ bf16 Us[64 * 64];
  __shared__ bf16 Ss[64 * 64];

  int tid = threadIdx.x;
  if (tid < 64) {
    int rr = tid < nrows ? tid : nrows - 1;
    toks[tid] = tl[rr];
    coefs[tid] = tid < nrows ? wlp[tid] : 0.0f;
  }
  __syncthreads();

  int lane = tid & 63, wv = tid >> 6;
  int srow = tid >> 3, scol = (tid & 7) * 8;
  int fr = lane & 15, fk = (lane >> 4) * 8;
  size_t tokA0 = (size_t)toks[srow] * D_DIM;
  size_t tokA1 = (size_t)toks[32 + srow] * D_DIM;
  const bf16* Ue = Ub + (size_t)e * RK * D_DIM;
  f32x4 acc1[4] = {};

  for (int k0 = 0; k0 < D_DIM; k0 += 64) {
    __syncthreads();
    gload16(encb + tokA0 + k0 + scol, &As[srow * 64 + scol]);
    gload16(encb + tokA1 + k0 + scol, &As[(32 + srow) * 64 + scol]);
    gload16(Ue + (size_t)srow * D_DIM + k0 + scol, &Us[srow * 64 + scol]);
    gload16(Ue + (size_t)(32 + srow) * D_DIM + k0 + scol, &Us[(32 + srow) * 64 + scol]);
    __syncthreads();
#pragma unroll
    for (int kk = 0; kk < 2; ++kk) {
      bf16x8 af = *(const bf16x8*)&As[(wv * 16 + fr) * 64 + kk * 32 + fk];
#pragma unroll
      for (int n = 0; n < 4; ++n) {
        bf16x8 bv = *(const bf16x8*)&Us[(n * 16 + fr) * 64 + kk * 32 + fk];
        acc1[n] = __builtin_amdgcn_mfma_f32_16x16x32_bf16(af, bv, acc1[n], 0, 0, 0);
      }
    }
  }
  int rg = (lane >> 4) * 4;
#pragma unroll
  for (int n = 0; n < 4; ++n)
#pragma unroll
    for (int r = 0; r < 4; ++r) {
      int row = wv * 16 + rg + r;
      float v = acc1[n][r];
      float s = v / (1.0f + __expf(-v));
      Ss[row * 64 + n * 16 + fr] = (bf16)(s * coefs[row]);
    }
  __syncthreads();
  bf16x8 a2[4][2];
#pragma unroll
  for (int m = 0; m < 4; ++m)
#pragma unroll
    for (int kk = 0; kk < 2; ++kk)
      a2[m][kk] = *(const bf16x8*)&Ss[(m * 16 + fr) * 64 + kk * 32 + fk];
  const bf16* Ve = Vb + (size_t)e * D_DIM * RK;
  int colbase = wv * 256;
  for (int nj = 0; nj < 16; ++nj) {
    int dcol = colbase + nj * 16 + fr;
    bf16x8 b0 = *(const bf16x8*)&Ve[(size_t)dcol * RK + fk];
    bf16x8 b1 = *(const bf16x8*)&Ve[(size_t)dcol * RK + 32 + fk];
#pragma unroll
    for (int m = 0; m < 4; ++m) {
      f32x4 a = {};
      a = __builtin_amdgcn_mfma_f32_16x16x32_bf16(a2[m][0], b0, a, 0, 0, 0);
      a = __builtin_amdgcn_mfma_f32_16x16x32_bf16(a2[m][1], b1, a, 0, 0, 0);
#pragma unroll
      for (int r = 0; r < 4; ++r) {
        int row = m * 16 + rg + r;
        if (row < nrows) {
          size_t off = (size_t)toks[row] * D_DIM + dcol;
          out[off] += a[r];
        }
      }
    }
  }
}

extern "C" void kernel_launch(void* const* d_in, const int* in_sizes, int n_in,
                              void* d_out, int out_size, void* d_ws, size_t ws_size,
                              hipStream_t stream) {
  const float* x   = (const float*)d_in[0];
  const float* We  = (const float*)d_in[1];
  const float* be  = (const float*)d_in[2];
  const float* Wg  = (const float*)d_in[3];
  const float* U   = (const float*)d_in[4];
  const float* V   = (const float*)d_in[5];
  const float* gam = (const float*)d_in[6];
  float* out = (float*)d_out;
  char* ws = (char*)d_ws;

  int*   cnt  = (int*)(ws + 0);                       // 128 B   (zeroed)
  float* G    = (float*)(ws + 256);                   // 64 KiB  (zeroed)
  float* bg   = (float*)(ws + 66048);                 // 64 B
  bf16*  xb   = (bf16*)(ws + 131072);                 // 32 MiB
  bf16*  encb = (bf16*)(ws + 131072 + 33554432);      // 32 MiB
  bf16*  Wb   = (bf16*)(ws + 131072 + 2 * 33554432);  // 2 MiB
  bf16*  Ubf  = (bf16*)(ws + 131072 + 2 * 33554432 + 2097152);
  bf16*  Vbf  = (bf16*)(ws + 131072 + 2 * 33554432 + 2 * 2097152);
  int*   lists= (int*)(ws + 131072 + 2 * 33554432 + 3 * 2097152);
  float* wl   = (float*)(ws + 131072 + 2 * 33554432 + 4 * 2097152);

  hipMemsetAsync(ws, 0, 66048, stream);

  k_cast<<<1024, 256, 0, stream>>>(We, Wb, 1048576 / 4);
  k_cast<<<1024, 256, 0, stream>>>(U, Ubf, 1048576 / 4);
  k_cast<<<1024, 256, 0, stream>>>(V, Vbf, 1048576 / 4);

  dim3 gg(4, 16, 8);
  k_gmat<<<gg, 256, 0, stream>>>(Wg, We, G);
  k_bgate<<<16, 256, 0, stream>>>(Wg, be, bg);

  k_gatecast<<<1024, 256, 0, stream>>>(x, G, bg, gam, xb, cnt, lists, wl);

  dim3 ge(8, 128);
  k_encgemm<<<ge, 256, 0, stream>>>(xb, Wb, be, out, encb);

  dim3 gx(16, 256);
  k_expert<<<gx, 256, 0, stream>>>(encb, Ubf, Vbf, cnt, lists, wl, out, 0);
  k_expert<<<gx, 256, 0, stream>>>(encb, Ubf, Vbf, cnt, lists, wl, out, 1);
}

// Round 5
// 477.974 us; speedup vs baseline: 1.1640x; 1.1640x over previous
//
#include <hip/hip_runtime.h>
#include <hip/hip_bf16.h>

#define D_DIM 1024
#define NE 16
#define RK 64
#define NTOK 16384

typedef __bf16 bf16;
typedef __bf16 bf16x8 __attribute__((ext_vector_type(8)));
typedef __bf16 bf16x4 __attribute__((ext_vector_type(4)));
typedef float f32x4 __attribute__((ext_vector_type(4)));

__device__ __forceinline__ void gload16(const void* g, void* l) {
  __builtin_amdgcn_global_load_lds((const __attribute__((address_space(1))) unsigned int*)g,
                                   (__attribute__((address_space(3))) unsigned int*)l,
                                   16, 0, 0);
}

// ---------------- casts (weights only) ----------------
__global__ void k_cast(const float* __restrict__ s, bf16* __restrict__ d, int n4) {
  int i = blockIdx.x * blockDim.x + threadIdx.x;
  if (i >= n4) return;
  float4 v = ((const float4*)s)[i];
  bf16x4 o = { (bf16)v.x, (bf16)v.y, (bf16)v.z, (bf16)v.w };
  ((bf16x4*)d)[i] = o;
}

// ---------------- G = W_gate @ W_enc  (fp64 partial sums, atomic combine) ----------------
__global__ void k_gmat(const float* __restrict__ Wg, const float* __restrict__ We,
                       float* __restrict__ G) {
  int d = blockIdx.x * 256 + threadIdx.x;
  int e = blockIdx.y;
  int j0 = blockIdx.z * 128;
  double a0 = 0.0, a1 = 0.0, a2 = 0.0, a3 = 0.0;
  for (int j = j0; j < j0 + 128; j += 4) {
    a0 += (double)Wg[e * D_DIM + j + 0] * (double)We[(size_t)(j + 0) * D_DIM + d];
    a1 += (double)Wg[e * D_DIM + j + 1] * (double)We[(size_t)(j + 1) * D_DIM + d];
    a2 += (double)Wg[e * D_DIM + j + 2] * (double)We[(size_t)(j + 2) * D_DIM + d];
    a3 += (double)Wg[e * D_DIM + j + 3] * (double)We[(size_t)(j + 3) * D_DIM + d];
  }
  atomicAdd(&G[e * D_DIM + d], (float)((a0 + a1) + (a2 + a3)));
}

// ---------------- bgate[e] = W_gate[e,:] . b_enc ----------------
__global__ void k_bgate(const float* __restrict__ Wg, const float* __restrict__ be,
                        float* __restrict__ bg) {
  __shared__ double red[256];
  int e = blockIdx.x, t = threadIdx.x;
  double a = 0.0;
  for (int j = t; j < D_DIM; j += 256) a += (double)Wg[e * D_DIM + j] * (double)be[j];
  red[t] = a; __syncthreads();
  for (int s = 128; s > 0; s >>= 1) { if (t < s) red[t] += red[t + s]; __syncthreads(); }
  if (t == 0) bg[e] = (float)red[0];
}

// ---------------- fused gating + x->bf16 cast (R5: expert-per-lane) ----------------
// Lane (g = lane&15 -> expert, s = lane>>4 -> d-slice). 8 tokens/wave.
// Per j-chunk(16 floats): 1 G float4 per lane (reused for all 8 tokens),
// 8 x float4 loads (same addr across 16 expert-lanes -> 1 line each, fully
// used by the 4 s-slices). acc[8] per lane -> ~40 VGPR, no spill (R4 had
// acc[4][16]=64 live -> compiler spilled: 751MB scratch writes).
// Lanes g<8 write bf16 cast for token g. Reduce over s via shfl_xor(16,32),
// transpose through 2KB LDS, serial top-2 scan (identical semantics to R3).
__global__ __launch_bounds__(256) void k_gatecast(const float* __restrict__ x,
                                                  const float* __restrict__ G,
                                                  const float* __restrict__ bg,
                                                  const float* __restrict__ gamma,
                                                  bf16* __restrict__ xb,
                                                  int* __restrict__ cnt,
                                                  int* __restrict__ lists,
                                                  float* __restrict__ wl) {
  __shared__ float Ls[4 * 8 * NE];  // [wave][token][expert]
  int tid = threadIdx.x;
  int wv = tid >> 6, lane = tid & 63;
  int g = lane & 15;   // expert owned by this lane
  int s = lane >> 4;   // d-slice 0..3
  int tokbase = (blockIdx.x * 4 + wv) * 8;
  const float* xp = x + (size_t)tokbase * D_DIM;
  const float* Gp = G + g * D_DIM;

  float acc[8] = {};
  for (int j0 = 0; j0 < D_DIM; j0 += 16) {
    int jo = j0 + s * 4;
    float4 gv = *(const float4*)(Gp + jo);
#pragma unroll
    for (int t = 0; t < 8; ++t) {
      float4 xv = *(const float4*)(xp + t * D_DIM + jo);
      acc[t] += xv.x * gv.x + xv.y * gv.y + xv.z * gv.z + xv.w * gv.w;
      if (g == t) {  // lanes g<8: this lane stores token g, slice s
        bf16x4 o = { (bf16)xv.x, (bf16)xv.y, (bf16)xv.z, (bf16)xv.w };
        *(bf16x4*)(xb + (size_t)(tokbase + t) * D_DIM + jo) = o;
      }
    }
  }
  // reduce partial dots across the 4 s-lanes (lanes g, g+16, g+32, g+48)
#pragma unroll
  for (int t = 0; t < 8; ++t) {
    acc[t] += __shfl_xor(acc[t], 16);
    acc[t] += __shfl_xor(acc[t], 32);
  }
  if (s == 0) {
#pragma unroll
    for (int t = 0; t < 8; ++t) Ls[wv * 128 + t * 16 + g] = acc[t];
  }
  __syncthreads();

  if (lane < 8) {
    int t = lane;
    int tok = tokbase + t;
    const float* lrow = &Ls[wv * 128 + t * 16];
    float v1 = -1e30f, v2 = -1e30f; int i1 = 0, i2 = 0;
#pragma unroll
    for (int e = 0; e < NE; ++e) {
      float v = lrow[e] + bg[e];
      if (v > v1) { v2 = v1; i2 = i1; v1 = v; i1 = e; }
      else if (v > v2) { v2 = v; i2 = e; }
    }
    float e1 = expf(v2 - v1);
    float den = 1.0f + e1 + 1e-12f;
    float w0 = (1.0f / den) * gamma[i1];
    float w1 = (e1 / den) * gamma[i2];
    int p0 = atomicAdd(&cnt[i1], 1);
    lists[(size_t)i1 * NTOK + p0] = tok;
    wl[(size_t)i1 * NTOK + p0] = w0;
    int p1 = atomicAdd(&cnt[NE + i2], 1);
    lists[(size_t)(NE + i2) * NTOK + p1] = tok;
    wl[(size_t)(NE + i2) * NTOK + p1] = w1;
  }
}

// ---------------- encoder GEMM: out = x @ W_enc^T + b (fp32) ; encb = bf16(out) ----------------
__global__ __launch_bounds__(256) void k_encgemm(const bf16* __restrict__ A,
                                                 const bf16* __restrict__ W,
                                                 const float* __restrict__ bias,
                                                 float* __restrict__ out,
                                                 bf16* __restrict__ encb) {
  __shared__ bf16 As[128 * 64];
  __shared__ bf16 Bs[128 * 64];
  const int K = D_DIM;
  int tid = threadIdx.x;
  int bn = blockIdx.x * 128;
  int bm = blockIdx.y * 128;
  int lane = tid & 63, wv = tid >> 6;
  int wm = (wv >> 1) * 64, wn = (wv & 1) * 64;
  int srow = tid >> 3, scol = (tid & 7) * 8;
  int fr = lane & 15, fk = (lane >> 4) * 8;
  f32x4 acc[4][4] = {};
  for (int k0 = 0; k0 < K; k0 += 64) {
    __syncthreads();
#pragma unroll
    for (int p = 0; p < 4; ++p) {
      int r = p * 32 + srow;
      gload16(A + (size_t)(bm + r) * K + k0 + scol, &As[r * 64 + scol]);
    }
#pragma unroll
    for (int p = 0; p < 4; ++p) {
      int r = p * 32 + srow;
      gload16(W + (size_t)(bn + r) * K + k0 + scol, &Bs[r * 64 + scol]);
    }
    __syncthreads();
#pragma unroll
    for (int kk = 0; kk < 2; ++kk) {
      bf16x8 af[4], bv[4];
#pragma unroll
      for (int m = 0; m < 4; ++m)
        af[m] = *(const bf16x8*)&As[(wm + m * 16 + fr) * 64 + kk * 32 + fk];
#pragma unroll
      for (int n = 0; n < 4; ++n)
        bv[n] = *(const bf16x8*)&Bs[(wn + n * 16 + fr) * 64 + kk * 32 + fk];
#pragma unroll
      for (int m = 0; m < 4; ++m)
#pragma unroll
        for (int n = 0; n < 4; ++n)
          acc[m][n] = __builtin_amdgcn_mfma_f32_16x16x32_bf16(af[m], bv[n], acc[m][n], 0, 0, 0);
    }
  }
  int rg = (lane >> 4) * 4;
#pragma unroll
  for (int n = 0; n < 4; ++n) {
    int col = bn + wn + n * 16 + fr;
    float bval = bias[col];
#pragma unroll
    for (int m = 0; m < 4; ++m) {
#pragma unroll
      for (int r = 0; r < 4; ++r) {
        int row = bm + wm + m * 16 + rg + r;
        float v = acc[m][n][r] + bval;
        out[(size_t)row * D_DIM + col] = v;
        encb[(size_t)row * D_DIM + col] = (bf16)v;
      }
    }
  }
}

// ---------------- expert kernel (one slot): gather 64 tokens, S=silu(enc U^T)*coef, out += S V^T ----------------
__global__ __launch_bounds__(256) void k_expert(const bf16* __restrict__ encb,
                                                const bf16* __restrict__ Ub,
                                                const bf16* __restrict__ Vb,
                                                const int* __restrict__ cnt,
                                                const int* __restrict__ lists,
                                                const float* __restrict__ wl,
                                                float* __restrict__ out, int slot) {
  int e = blockIdx.x;
  int c = cnt[slot * NE + e];
  int t0 = blockIdx.y * 64;
  if (t0 >= c) return;
  int nrows = c - t0; if (nrows > 64) nrows = 64;
  const int* tl = lists + (size_t)(slot * NE + e) * NTOK + t0;
  const float* wlp = wl + (size_t)(slot * NE + e) * NTOK + t0;

  __shared__ int toks[64];
  __shared__ float coefs[64];
  __shared__ bf16 As[64 * 64];
  __shared__ bf16 Us[64 * 64];
  __shared__ bf16 Ss[64 * 64];

  int tid = threadIdx.x;
  if (tid < 64) {
    int rr = tid < nrows ? tid : nrows - 1;
    toks[tid] = tl[rr];
    coefs[tid] = tid < nrows ? wlp[tid] : 0.0f;
  }
  __syncthreads();

  int lane = tid & 63, wv = tid >> 6;
  int srow = tid >> 3, scol = (tid & 7) * 8;
  int fr = lane & 15, fk = (lane >> 4) * 8;
  size_t tokA0 = (size_t)toks[srow] * D_DIM;
  size_t tokA1 = (size_t)toks[32 + srow] * D_DIM;
  const bf16* Ue = Ub + (size_t)e * RK * D_DIM;
  f32x4 acc1[4] = {};

  for (int k0 = 0; k0 < D_DIM; k0 += 64) {
    __syncthreads();
    gload16(encb + tokA0 + k0 + scol, &As[srow * 64 + scol]);
    gload16(encb + tokA1 + k0 + scol, &As[(32 + srow) * 64 + scol]);
    gload16(Ue + (size_t)srow * D_DIM + k0 + scol, &Us[srow * 64 + scol]);
    gload16(Ue + (size_t)(32 + srow) * D_DIM + k0 + scol, &Us[(32 + srow) * 64 + scol]);
    __syncthreads();
#pragma unroll
    for (int kk = 0; kk < 2; ++kk) {
      bf16x8 af = *(const bf16x8*)&As[(wv * 16 + fr) * 64 + kk * 32 + fk];
#pragma unroll
      for (int n = 0; n < 4; ++n) {
        bf16x8 bv = *(const bf16x8*)&Us[(n * 16 + fr) * 64 + kk * 32 + fk];
        acc1[n] = __builtin_amdgcn_mfma_f32_16x16x32_bf16(af, bv, acc1[n], 0, 0, 0);
      }
    }
  }
  int rg = (lane >> 4) * 4;
#pragma unroll
  for (int n = 0; n < 4; ++n)
#pragma unroll
    for (int r = 0; r < 4; ++r) {
      int row = wv * 16 + rg + r;
      float v = acc1[n][r];
      float s = v / (1.0f + __expf(-v));
      Ss[row * 64 + n * 16 + fr] = (bf16)(s * coefs[row]);
    }
  __syncthreads();
  bf16x8 a2[4][2];
#pragma unroll
  for (int m = 0; m < 4; ++m)
#pragma unroll
    for (int kk = 0; kk < 2; ++kk)
      a2[m][kk] = *(const bf16x8*)&Ss[(m * 16 + fr) * 64 + kk * 32 + fk];
  const bf16* Ve = Vb + (size_t)e * D_DIM * RK;
  int colbase = wv * 256;
  for (int nj = 0; nj < 16; ++nj) {
    int dcol = colbase + nj * 16 + fr;
    bf16x8 b0 = *(const bf16x8*)&Ve[(size_t)dcol * RK + fk];
    bf16x8 b1 = *(const bf16x8*)&Ve[(size_t)dcol * RK + 32 + fk];
#pragma unroll
    for (int m = 0; m < 4; ++m) {
      f32x4 a = {};
      a = __builtin_amdgcn_mfma_f32_16x16x32_bf16(a2[m][0], b0, a, 0, 0, 0);
      a = __builtin_amdgcn_mfma_f32_16x16x32_bf16(a2[m][1], b1, a, 0, 0, 0);
#pragma unroll
      for (int r = 0; r < 4; ++r) {
        int row = m * 16 + rg + r;
        if (row < nrows) {
          size_t off = (size_t)toks[row] * D_DIM + dcol;
          out[off] += a[r];
        }
      }
    }
  }
}

extern "C" void kernel_launch(void* const* d_in, const int* in_sizes, int n_in,
                              void* d_out, int out_size, void* d_ws, size_t ws_size,
                              hipStream_t stream) {
  const float* x   = (const float*)d_in[0];
  const float* We  = (const float*)d_in[1];
  const float* be  = (const float*)d_in[2];
  const float* Wg  = (const float*)d_in[3];
  const float* U   = (const float*)d_in[4];
  const float* V   = (const float*)d_in[5];
  const float* gam = (const float*)d_in[6];
  float* out = (float*)d_out;
  char* ws = (char*)d_ws;

  int*   cnt  = (int*)(ws + 0);                       // 128 B   (zeroed)
  float* G    = (float*)(ws + 256);                   // 64 KiB  (zeroed)
  float* bg   = (float*)(ws + 66048);                 // 64 B
  bf16*  xb   = (bf16*)(ws + 131072);                 // 32 MiB
  bf16*  encb = (bf16*)(ws + 131072 + 33554432);      // 32 MiB
  bf16*  Wb   = (bf16*)(ws + 131072 + 2 * 33554432);  // 2 MiB
  bf16*  Ubf  = (bf16*)(ws + 131072 + 2 * 33554432 + 2097152);
  bf16*  Vbf  = (bf16*)(ws + 131072 + 2 * 33554432 + 2 * 2097152);
  int*   lists= (int*)(ws + 131072 + 2 * 33554432 + 3 * 2097152);
  float* wl   = (float*)(ws + 131072 + 2 * 33554432 + 4 * 2097152);

  hipMemsetAsync(ws, 0, 66048, stream);

  k_cast<<<1024, 256, 0, stream>>>(We, Wb, 1048576 / 4);
  k_cast<<<1024, 256, 0, stream>>>(U, Ubf, 1048576 / 4);
  k_cast<<<1024, 256, 0, stream>>>(V, Vbf, 1048576 / 4);

  dim3 gg(4, 16, 8);
  k_gmat<<<gg, 256, 0, stream>>>(Wg, We, G);
  k_bgate<<<16, 256, 0, stream>>>(Wg, be, bg);

  k_gatecast<<<512, 256, 0, stream>>>(x, G, bg, gam, xb, cnt, lists, wl);

  dim3 ge(8, 128);
  k_encgemm<<<ge, 256, 0, stream>>>(xb, Wb, be, out, encb);

  dim3 gx(16, 256);
  k_expert<<<gx, 256, 0, stream>>>(encb, Ubf, Vbf, cnt, lists, wl, out, 0);
  k_expert<<<gx, 256, 0, stream>>>(encb, Ubf, Vbf, cnt, lists, wl, out, 1);
}

// Round 6
// 458.694 us; speedup vs baseline: 1.2129x; 1.0420x over previous
//
#include <hip/hip_runtime.h>
#include <hip/hip_bf16.h>

#define D_DIM 1024
#define NE 16
#define RK 64
#define NTOK 16384

typedef __bf16 bf16;
typedef __bf16 bf16x8 __attribute__((ext_vector_type(8)));
typedef __bf16 bf16x4 __attribute__((ext_vector_type(4)));
typedef float f32x4 __attribute__((ext_vector_type(4)));

__device__ __forceinline__ void gload16(const void* g, void* l) {
  __builtin_amdgcn_global_load_lds((const __attribute__((address_space(1))) unsigned int*)g,
                                   (__attribute__((address_space(3))) unsigned int*)l,
                                   16, 0, 0);
}

// ---------------- casts (weights only) ----------------
__global__ void k_cast(const float* __restrict__ s, bf16* __restrict__ d, int n4) {
  int i = blockIdx.x * blockDim.x + threadIdx.x;
  if (i >= n4) return;
  float4 v = ((const float4*)s)[i];
  bf16x4 o = { (bf16)v.x, (bf16)v.y, (bf16)v.z, (bf16)v.w };
  ((bf16x4*)d)[i] = o;
}

// ---------------- G = W_gate @ W_enc  (fp64 partial sums, atomic combine) ----------------
__global__ void k_gmat(const float* __restrict__ Wg, const float* __restrict__ We,
                       float* __restrict__ G) {
  int d = blockIdx.x * 256 + threadIdx.x;
  int e = blockIdx.y;
  int j0 = blockIdx.z * 128;
  double a0 = 0.0, a1 = 0.0, a2 = 0.0, a3 = 0.0;
  for (int j = j0; j < j0 + 128; j += 4) {
    a0 += (double)Wg[e * D_DIM + j + 0] * (double)We[(size_t)(j + 0) * D_DIM + d];
    a1 += (double)Wg[e * D_DIM + j + 1] * (double)We[(size_t)(j + 1) * D_DIM + d];
    a2 += (double)Wg[e * D_DIM + j + 2] * (double)We[(size_t)(j + 2) * D_DIM + d];
    a3 += (double)Wg[e * D_DIM + j + 3] * (double)We[(size_t)(j + 3) * D_DIM + d];
  }
  atomicAdd(&G[e * D_DIM + d], (float)((a0 + a1) + (a2 + a3)));
}

// ---------------- bgate[e] = W_gate[e,:] . b_enc ----------------
__global__ void k_bgate(const float* __restrict__ Wg, const float* __restrict__ be,
                        float* __restrict__ bg) {
  __shared__ double red[256];
  int e = blockIdx.x, t = threadIdx.x;
  double a = 0.0;
  for (int j = t; j < D_DIM; j += 256) a += (double)Wg[e * D_DIM + j] * (double)be[j];
  red[t] = a; __syncthreads();
  for (int s = 128; s > 0; s >>= 1) { if (t < s) red[t] += red[t + s]; __syncthreads(); }
  if (t == 0) bg[e] = (float)red[0];
}

// ---------------- fused gating + x->bf16 cast (R6: 2 tokens/wave, prefetch) ----------------
// R5 post-mortem: 8 tok/wave -> only 2048 waves = 2 waves/SIMD (Occ 21%),
// latency-bound. R6: 2 tok/wave -> 8192 waves = 8 waves/SIMD (100% target),
// plus register double-buffer prefetch of (gv, x0, x1). Per-lane accumulation
// order identical to R5 (4-term fp32 dots per chunk, xor16+xor32 reduce).
__global__ __launch_bounds__(256) void k_gatecast(const float* __restrict__ x,
                                                  const float* __restrict__ G,
                                                  const float* __restrict__ bg,
                                                  const float* __restrict__ gamma,
                                                  bf16* __restrict__ xb,
                                                  int* __restrict__ cnt,
                                                  int* __restrict__ lists,
                                                  float* __restrict__ wl) {
  __shared__ float Ls[4 * 2 * NE];  // [wave][token][expert]
  int tid = threadIdx.x;
  int wv = tid >> 6, lane = tid & 63;
  int g = lane & 15;   // expert owned by this lane
  int s = lane >> 4;   // d-slice 0..3
  int tokbase = (blockIdx.x * 4 + wv) * 2;
  const float* xq = x + (size_t)tokbase * D_DIM + s * 4;
  const float* Gp = G + g * D_DIM + s * 4;
  bf16* xo = xb + (size_t)tokbase * D_DIM + s * 4;

  float acc0 = 0.0f, acc1 = 0.0f;
  float4 gv = *(const float4*)Gp;
  float4 x0 = *(const float4*)xq;
  float4 x1 = *(const float4*)(xq + D_DIM);
  for (int j0 = 0; j0 < D_DIM; j0 += 16) {
    int jn = j0 + 16;
    int jp = (jn < D_DIM) ? jn : 0;  // last-iter prefetch clamped (discarded)
    float4 gn = *(const float4*)(Gp + jp);
    float4 xn0 = *(const float4*)(xq + jp);
    float4 xn1 = *(const float4*)(xq + D_DIM + jp);
    acc0 += x0.x * gv.x + x0.y * gv.y + x0.z * gv.z + x0.w * gv.w;
    acc1 += x1.x * gv.x + x1.y * gv.y + x1.z * gv.z + x1.w * gv.w;
    if (g == 0) {
      bf16x4 o = { (bf16)x0.x, (bf16)x0.y, (bf16)x0.z, (bf16)x0.w };
      *(bf16x4*)(xo + j0) = o;
    }
    if (g == 1) {
      bf16x4 o = { (bf16)x1.x, (bf16)x1.y, (bf16)x1.z, (bf16)x1.w };
      *(bf16x4*)(xo + D_DIM + j0) = o;
    }
    gv = gn; x0 = xn0; x1 = xn1;
  }
  acc0 += __shfl_xor(acc0, 16); acc0 += __shfl_xor(acc0, 32);
  acc1 += __shfl_xor(acc1, 16); acc1 += __shfl_xor(acc1, 32);
  if (s == 0) {
    Ls[wv * 32 + g] = acc0;
    Ls[wv * 32 + 16 + g] = acc1;
  }
  __syncthreads();

  if (lane < 2) {
    int t = lane;
    int tok = tokbase + t;
    const float* lrow = &Ls[wv * 32 + t * 16];
    float v1 = -1e30f, v2 = -1e30f; int i1 = 0, i2 = 0;
#pragma unroll
    for (int e = 0; e < NE; ++e) {
      float v = lrow[e] + bg[e];
      if (v > v1) { v2 = v1; i2 = i1; v1 = v; i1 = e; }
      else if (v > v2) { v2 = v; i2 = e; }
    }
    float e1 = expf(v2 - v1);
    float den = 1.0f + e1 + 1e-12f;
    float w0 = (1.0f / den) * gamma[i1];
    float w1 = (e1 / den) * gamma[i2];
    int p0 = atomicAdd(&cnt[i1], 1);
    lists[(size_t)i1 * NTOK + p0] = tok;
    wl[(size_t)i1 * NTOK + p0] = w0;
    int p1 = atomicAdd(&cnt[NE + i2], 1);
    lists[(size_t)(NE + i2) * NTOK + p1] = tok;
    wl[(size_t)(NE + i2) * NTOK + p1] = w1;
  }
}

// ---------------- encoder GEMM: out = x @ W_enc^T + b (fp32) ; encb = bf16(out) ----------------
__global__ __launch_bounds__(256) void k_encgemm(const bf16* __restrict__ A,
                                                 const bf16* __restrict__ W,
                                                 const float* __restrict__ bias,
                                                 float* __restrict__ out,
                                                 bf16* __restrict__ encb) {
  __shared__ bf16 As[128 * 64];
  __shared__ bf16 Bs[128 * 64];
  const int K = D_DIM;
  int tid = threadIdx.x;
  int bn = blockIdx.x * 128;
  int bm = blockIdx.y * 128;
  int lane = tid & 63, wv = tid >> 6;
  int wm = (wv >> 1) * 64, wn = (wv & 1) * 64;
  int srow = tid >> 3, scol = (tid & 7) * 8;
  int fr = lane & 15, fk = (lane >> 4) * 8;
  f32x4 acc[4][4] = {};
  for (int k0 = 0; k0 < K; k0 += 64) {
    __syncthreads();
#pragma unroll
    for (int p = 0; p < 4; ++p) {
      int r = p * 32 + srow;
      gload16(A + (size_t)(bm + r) * K + k0 + scol, &As[r * 64 + scol]);
    }
#pragma unroll
    for (int p = 0; p < 4; ++p) {
      int r = p * 32 + srow;
      gload16(W + (size_t)(bn + r) * K + k0 + scol, &Bs[r * 64 + scol]);
    }
    __syncthreads();
#pragma unroll
    for (int kk = 0; kk < 2; ++kk) {
      bf16x8 af[4], bv[4];
#pragma unroll
      for (int m = 0; m < 4; ++m)
        af[m] = *(const bf16x8*)&As[(wm + m * 16 + fr) * 64 + kk * 32 + fk];
#pragma unroll
      for (int n = 0; n < 4; ++n)
        bv[n] = *(const bf16x8*)&Bs[(wn + n * 16 + fr) * 64 + kk * 32 + fk];
#pragma unroll
      for (int m = 0; m < 4; ++m)
#pragma unroll
        for (int n = 0; n < 4; ++n)
          acc[m][n] = __builtin_amdgcn_mfma_f32_16x16x32_bf16(af[m], bv[n], acc[m][n], 0, 0, 0);
    }
  }
  int rg = (lane >> 4) * 4;
#pragma unroll
  for (int n = 0; n < 4; ++n) {
    int col = bn + wn + n * 16 + fr;
    float bval = bias[col];
#pragma unroll
    for (int m = 0; m < 4; ++m) {
#pragma unroll
      for (int r = 0; r < 4; ++r) {
        int row = bm + wm + m * 16 + rg + r;
        float v = acc[m][n][r] + bval;
        out[(size_t)row * D_DIM + col] = v;
        encb[(size_t)row * D_DIM + col] = (bf16)v;
      }
    }
  }
}

// ---------------- expert kernel (one slot): gather 64 tokens, S=silu(enc U^T)*coef, out += S V^T ----------------
__global__ __launch_bounds__(256) void k_expert(const bf16* __restrict__ encb,
                                                const bf16* __restrict__ Ub,
                                                const bf16* __restrict__ Vb,
                                                const int* __restrict__ cnt,
                                                const int* __restrict__ lists,
                                                const float* __restrict__ wl,
                                                float* __restrict__ out, int slot) {
  int e = blockIdx.x;
  int c = cnt[slot * NE + e];
  int t0 = blockIdx.y * 64;
  if (t0 >= c) return;
  int nrows = c - t0; if (nrows > 64) nrows = 64;
  const int* tl = lists + (size_t)(slot * NE + e) * NTOK + t0;
  const float* wlp = wl + (size_t)(slot * NE + e) * NTOK + t0;

  __shared__ int toks[64];
  __shared__ float coefs[64];
  __shared__ bf16 As[64 * 64];
  __shared__ bf16 Us[64 * 64];
  __shared__ bf16 Ss[64 * 64];

  int tid = threadIdx.x;
  if (tid < 64) {
    int rr = tid < nrows ? tid : nrows - 1;
    toks[tid] = tl[rr];
    coefs[tid] = tid < nrows ? wlp[tid] : 0.0f;
  }
  __syncthreads();

  int lane = tid & 63, wv = tid >> 6;
  int srow = tid >> 3, scol = (tid & 7) * 8;
  int fr = lane & 15, fk = (lane >> 4) * 8;
  size_t tokA0 = (size_t)toks[srow] * D_DIM;
  size_t tokA1 = (size_t)toks[32 + srow] * D_DIM;
  const bf16* Ue = Ub + (size_t)e * RK * D_DIM;
  f32x4 acc1[4] = {};

  for (int k0 = 0; k0 < D_DIM; k0 += 64) {
    __syncthreads();
    gload16(encb + tokA0 + k0 + scol, &As[srow * 64 + scol]);
    gload16(encb + tokA1 + k0 + scol, &As[(32 + srow) * 64 + scol]);
    gload16(Ue + (size_t)srow * D_DIM + k0 + scol, &Us[srow * 64 + scol]);
    gload16(Ue + (size_t)(32 + srow) * D_DIM + k0 + scol, &Us[(32 + srow) * 64 + scol]);
    __syncthreads();
#pragma unroll
    for (int kk = 0; kk < 2; ++kk) {
      bf16x8 af = *(const bf16x8*)&As[(wv * 16 + fr) * 64 + kk * 32 + fk];
#pragma unroll
      for (int n = 0; n < 4; ++n) {
        bf16x8 bv = *(const bf16x8*)&Us[(n * 16 + fr) * 64 + kk * 32 + fk];
        acc1[n] = __builtin_amdgcn_mfma_f32_16x16x32_bf16(af, bv, acc1[n], 0, 0, 0);
      }
    }
  }
  int rg = (lane >> 4) * 4;
#pragma unroll
  for (int n = 0; n < 4; ++n)
#pragma unroll
    for (int r = 0; r < 4; ++r) {
      int row = wv * 16 + rg + r;
      float v = acc1[n][r];
      float s = v / (1.0f + __expf(-v));
      Ss[row * 64 + n * 16 + fr] = (bf16)(s * coefs[row]);
    }
  __syncthreads();
  bf16x8 a2[4][2];
#pragma unroll
  for (int m = 0; m < 4; ++m)
#pragma unroll
    for (int kk = 0; kk < 2; ++kk)
      a2[m][kk] = *(const bf16x8*)&Ss[(m * 16 + fr) * 64 + kk * 32 + fk];
  const bf16* Ve = Vb + (size_t)e * D_DIM * RK;
  int colbase = wv * 256;
  for (int nj = 0; nj < 16; ++nj) {
    int dcol = colbase + nj * 16 + fr;
    bf16x8 b0 = *(const bf16x8*)&Ve[(size_t)dcol * RK + fk];
    bf16x8 b1 = *(const bf16x8*)&Ve[(size_t)dcol * RK + 32 + fk];
#pragma unroll
    for (int m = 0; m < 4; ++m) {
      f32x4 a = {};
      a = __builtin_amdgcn_mfma_f32_16x16x32_bf16(a2[m][0], b0, a, 0, 0, 0);
      a = __builtin_amdgcn_mfma_f32_16x16x32_bf16(a2[m][1], b1, a, 0, 0, 0);
#pragma unroll
      for (int r = 0; r < 4; ++r) {
        int row = m * 16 + rg + r;
        if (row < nrows) {
          size_t off = (size_t)toks[row] * D_DIM + dcol;
          out[off] += a[r];
        }
      }
    }
  }
}

extern "C" void kernel_launch(void* const* d_in, const int* in_sizes, int n_in,
                              void* d_out, int out_size, void* d_ws, size_t ws_size,
                              hipStream_t stream) {
  const float* x   = (const float*)d_in[0];
  const float* We  = (const float*)d_in[1];
  const float* be  = (const float*)d_in[2];
  const float* Wg  = (const float*)d_in[3];
  const float* U   = (const float*)d_in[4];
  const float* V   = (const float*)d_in[5];
  const float* gam = (const float*)d_in[6];
  float* out = (float*)d_out;
  char* ws = (char*)d_ws;

  int*   cnt  = (int*)(ws + 0);                       // 128 B   (zeroed)
  float* G    = (float*)(ws + 256);                   // 64 KiB  (zeroed)
  float* bg   = (float*)(ws + 66048);                 // 64 B
  bf16*  xb   = (bf16*)(ws + 131072);                 // 32 MiB
  bf16*  encb = (bf16*)(ws + 131072 + 33554432);      // 32 MiB
  bf16*  Wb   = (bf16*)(ws + 131072 + 2 * 33554432);  // 2 MiB
  bf16*  Ubf  = (bf16*)(ws + 131072 + 2 * 33554432 + 2097152);
  bf16*  Vbf  = (bf16*)(ws + 131072 + 2 * 33554432 + 2 * 2097152);
  int*   lists= (int*)(ws + 131072 + 2 * 33554432 + 3 * 2097152);
  float* wl   = (float*)(ws + 131072 + 2 * 33554432 + 4 * 2097152);

  hipMemsetAsync(ws, 0, 66048, stream);

  k_cast<<<1024, 256, 0, stream>>>(We, Wb, 1048576 / 4);
  k_cast<<<1024, 256, 0, stream>>>(U, Ubf, 1048576 / 4);
  k_cast<<<1024, 256, 0, stream>>>(V, Vbf, 1048576 / 4);

  dim3 gg(4, 16, 8);
  k_gmat<<<gg, 256, 0, stream>>>(Wg, We, G);
  k_bgate<<<16, 256, 0, stream>>>(Wg, be, bg);

  k_gatecast<<<2048, 256, 0, stream>>>(x, G, bg, gam, xb, cnt, lists, wl);

  dim3 ge(8, 128);
  k_encgemm<<<ge, 256, 0, stream>>>(xb, Wb, be, out, encb);

  dim3 gx(16, 256);
  k_expert<<<gx, 256, 0, stream>>>(encb, Ubf, Vbf, cnt, lists, wl, out, 0);
  k_expert<<<gx, 256, 0, stream>>>(encb, Ubf, Vbf, cnt, lists, wl, out, 1);
}

// Round 7
// 424.101 us; speedup vs baseline: 1.3119x; 1.0816x over previous
//
#include <hip/hip_runtime.h>
#include <hip/hip_bf16.h>

#define D_DIM 1024
#define NE 16
#define RK 64
#define NTOK 16384

typedef __bf16 bf16;
typedef __bf16 bf16x8 __attribute__((ext_vector_type(8)));
typedef __bf16 bf16x4 __attribute__((ext_vector_type(4)));
typedef float f32x4 __attribute__((ext_vector_type(4)));

__device__ __forceinline__ void gload16(const void* g, void* l) {
  __builtin_amdgcn_global_load_lds((const __attribute__((address_space(1))) unsigned int*)g,
                                   (__attribute__((address_space(3))) unsigned int*)l,
                                   16, 0, 0);
}

// ---------------- casts (weights only) ----------------
__global__ void k_cast(const float* __restrict__ s, bf16* __restrict__ d, int n4) {
  int i = blockIdx.x * blockDim.x + threadIdx.x;
  if (i >= n4) return;
  float4 v = ((const float4*)s)[i];
  bf16x4 o = { (bf16)v.x, (bf16)v.y, (bf16)v.z, (bf16)v.w };
  ((bf16x4*)d)[i] = o;
}

// ---------------- Gt = (W_gate @ W_enc)^T stored [d][e]  (fp64 partials, atomic) ----------------
// R7: TRANSPOSED layout so gating loads are line-sequential, not 16-line gathers.
__global__ void k_gmat(const float* __restrict__ Wg, const float* __restrict__ We,
                       float* __restrict__ Gt) {
  int d = blockIdx.x * 256 + threadIdx.x;
  int e = blockIdx.y;
  int j0 = blockIdx.z * 128;
  double a0 = 0.0, a1 = 0.0, a2 = 0.0, a3 = 0.0;
  for (int j = j0; j < j0 + 128; j += 4) {
    a0 += (double)Wg[e * D_DIM + j + 0] * (double)We[(size_t)(j + 0) * D_DIM + d];
    a1 += (double)Wg[e * D_DIM + j + 1] * (double)We[(size_t)(j + 1) * D_DIM + d];
    a2 += (double)Wg[e * D_DIM + j + 2] * (double)We[(size_t)(j + 2) * D_DIM + d];
    a3 += (double)Wg[e * D_DIM + j + 3] * (double)We[(size_t)(j + 3) * D_DIM + d];
  }
  atomicAdd(&Gt[d * NE + e], (float)((a0 + a1) + (a2 + a3)));
}

// ---------------- bgate[e] = W_gate[e,:] . b_enc ----------------
__global__ void k_bgate(const float* __restrict__ Wg, const float* __restrict__ be,
                        float* __restrict__ bg) {
  __shared__ double red[256];
  int e = blockIdx.x, t = threadIdx.x;
  double a = 0.0;
  for (int j = t; j < D_DIM; j += 256) a += (double)Wg[e * D_DIM + j] * (double)be[j];
  red[t] = a; __syncthreads();
  for (int s = 128; s > 0; s >>= 1) { if (t < s) red[t] += red[t + s]; __syncthreads(); }
  if (t == 0) bg[e] = (float)red[0];
}

// ---------------- fused gating + x->bf16 cast (R7: Gt layout + tail cast) ----------------
// R6 post-mortem: G loads gathered 16 lines/instr (expert rows 4KB apart) ->
// latency-bound. R7: Gt[d][e] layout -> each G-load instr touches 4 sequential
// half-lines; x float4 1 line/instr; bf16 cast moved to a coalesced tail pass
// (512B/store-instr) instead of exec-masked 8B scatters in the hot loop.
// Summation structure identical to R6 (64 chunks x 4-term quads, xor16+xor32).
__global__ __launch_bounds__(256) void k_gatecast(const float* __restrict__ x,
                                                  const float* __restrict__ Gt,
                                                  const float* __restrict__ bg,
                                                  const float* __restrict__ gamma,
                                                  bf16* __restrict__ xb,
                                                  int* __restrict__ cnt,
                                                  int* __restrict__ lists,
                                                  float* __restrict__ wl) {
  __shared__ float Ls[4 * 2 * NE];  // [wave][token][expert]
  int tid = threadIdx.x;
  int wv = tid >> 6, lane = tid & 63;
  int g = lane & 15;   // expert owned by this lane
  int s = lane >> 4;   // j-quad slice 0..3
  int tokbase = (blockIdx.x * 4 + wv) * 2;
  const float* xq = x + (size_t)tokbase * D_DIM + s * 4;
  const float* Gq = Gt + (size_t)(s * 4) * NE + g;   // + j0*NE per chunk

  float acc0 = 0.0f, acc1 = 0.0f;
  float gt0 = Gq[0 * NE], gt1 = Gq[1 * NE], gt2 = Gq[2 * NE], gt3 = Gq[3 * NE];
  float4 x0 = *(const float4*)xq;
  float4 x1 = *(const float4*)(xq + D_DIM);
  for (int j0 = 0; j0 < D_DIM; j0 += 16) {
    int jn = j0 + 16;
    int jp = (jn < D_DIM) ? jn : 0;  // last-iter prefetch clamped (discarded)
    const float* Gn = Gq + (size_t)jp * NE;
    float gn0 = Gn[0 * NE], gn1 = Gn[1 * NE], gn2 = Gn[2 * NE], gn3 = Gn[3 * NE];
    float4 xn0 = *(const float4*)(xq + jp);
    float4 xn1 = *(const float4*)(xq + D_DIM + jp);
    acc0 += x0.x * gt0 + x0.y * gt1 + x0.z * gt2 + x0.w * gt3;
    acc1 += x1.x * gt0 + x1.y * gt1 + x1.z * gt2 + x1.w * gt3;
    gt0 = gn0; gt1 = gn1; gt2 = gn2; gt3 = gn3;
    x0 = xn0; x1 = xn1;
  }
  acc0 += __shfl_xor(acc0, 16); acc0 += __shfl_xor(acc0, 32);
  acc1 += __shfl_xor(acc1, 16); acc1 += __shfl_xor(acc1, 32);
  if (s == 0) {
    Ls[wv * 32 + g] = acc0;
    Ls[wv * 32 + 16 + g] = acc1;
  }

  // tail cast: coalesced re-read (L1/L2-hot) + bf16x4 stores (512B/instr)
#pragma unroll
  for (int t = 0; t < 2; ++t) {
    const float4* xrow = (const float4*)(x + (size_t)(tokbase + t) * D_DIM);
    bf16x4* orow = (bf16x4*)(xb + (size_t)(tokbase + t) * D_DIM);
#pragma unroll
    for (int r = 0; r < 4; ++r) {
      float4 v = xrow[lane + 64 * r];
      bf16x4 o = { (bf16)v.x, (bf16)v.y, (bf16)v.z, (bf16)v.w };
      orow[lane + 64 * r] = o;
    }
  }
  __syncthreads();

  if (lane < 2) {
    int t = lane;
    int tok = tokbase + t;
    const float* lrow = &Ls[wv * 32 + t * 16];
    float v1 = -1e30f, v2 = -1e30f; int i1 = 0, i2 = 0;
#pragma unroll
    for (int e = 0; e < NE; ++e) {
      float v = lrow[e] + bg[e];
      if (v > v1) { v2 = v1; i2 = i1; v1 = v; i1 = e; }
      else if (v > v2) { v2 = v; i2 = e; }
    }
    float e1 = expf(v2 - v1);
    float den = 1.0f + e1 + 1e-12f;
    float w0 = (1.0f / den) * gamma[i1];
    float w1 = (e1 / den) * gamma[i2];
    int p0 = atomicAdd(&cnt[i1], 1);
    lists[(size_t)i1 * NTOK + p0] = tok;
    wl[(size_t)i1 * NTOK + p0] = w0;
    int p1 = atomicAdd(&cnt[NE + i2], 1);
    lists[(size_t)(NE + i2) * NTOK + p1] = tok;
    wl[(size_t)(NE + i2) * NTOK + p1] = w1;
  }
}

// ---------------- encoder GEMM: out = x @ W_enc^T + b (fp32) ; encb = bf16(out) ----------------
__global__ __launch_bounds__(256) void k_encgemm(const bf16* __restrict__ A,
                                                 const bf16* __restrict__ W,
                                                 const float* __restrict__ bias,
                                                 float* __restrict__ out,
                                                 bf16* __restrict__ encb) {
  __shared__ bf16 As[128 * 64];
  __shared__ bf16 Bs[128 * 64];
  const int K = D_DIM;
  int tid = threadIdx.x;
  int bn = blockIdx.x * 128;
  int bm = blockIdx.y * 128;
  int lane = tid & 63, wv = tid >> 6;
  int wm = (wv >> 1) * 64, wn = (wv & 1) * 64;
  int srow = tid >> 3, scol = (tid & 7) * 8;
  int fr = lane & 15, fk = (lane >> 4) * 8;
  f32x4 acc[4][4] = {};
  for (int k0 = 0; k0 < K; k0 += 64) {
    __syncthreads();
#pragma unroll
    for (int p = 0; p < 4; ++p) {
      int r = p * 32 + srow;
      gload16(A + (size_t)(bm + r) * K + k0 + scol, &As[r * 64 + scol]);
    }
#pragma unroll
    for (int p = 0; p < 4; ++p) {
      int r = p * 32 + srow;
      gload16(W + (size_t)(bn + r) * K + k0 + scol, &Bs[r * 64 + scol]);
    }
    __syncthreads();
#pragma unroll
    for (int kk = 0; kk < 2; ++kk) {
      bf16x8 af[4], bv[4];
#pragma unroll
      for (int m = 0; m < 4; ++m)
        af[m] = *(const bf16x8*)&As[(wm + m * 16 + fr) * 64 + kk * 32 + fk];
#pragma unroll
      for (int n = 0; n < 4; ++n)
        bv[n] = *(const bf16x8*)&Bs[(wn + n * 16 + fr) * 64 + kk * 32 + fk];
#pragma unroll
      for (int m = 0; m < 4; ++m)
#pragma unroll
        for (int n = 0; n < 4; ++n)
          acc[m][n] = __builtin_amdgcn_mfma_f32_16x16x32_bf16(af[m], bv[n], acc[m][n], 0, 0, 0);
    }
  }
  int rg = (lane >> 4) * 4;
#pragma unroll
  for (int n = 0; n < 4; ++n) {
    int col = bn + wn + n * 16 + fr;
    float bval = bias[col];
#pragma unroll
    for (int m = 0; m < 4; ++m) {
#pragma unroll
      for (int r = 0; r < 4; ++r) {
        int row = bm + wm + m * 16 + rg + r;
        float v = acc[m][n][r] + bval;
        out[(size_t)row * D_DIM + col] = v;
        encb[(size_t)row * D_DIM + col] = (bf16)v;
      }
    }
  }
}

// ---------------- expert kernel (one slot): gather 64 tokens, S=silu(enc U^T)*coef, out += S V^T ----------------
__global__ __launch_bounds__(256) void k_expert(const bf16* __restrict__ encb,
                                                const bf16* __restrict__ Ub,
                                                const bf16* __restrict__ Vb,
                                                const int* __restrict__ cnt,
                                                const int* __restrict__ lists,
                                                const float* __restrict__ wl,
                                                float* __restrict__ out, int slot) {
  int e = blockIdx.x;
  int c = cnt[slot * NE + e];
  int t0 = blockIdx.y * 64;
  if (t0 >= c) return;
  int nrows = c - t0; if (nrows > 64) nrows = 64;
  const int* tl = lists + (size_t)(slot * NE + e) * NTOK + t0;
  const float* wlp = wl + (size_t)(slot * NE + e) * NTOK + t0;

  __shared__ int toks[64];
  __shared__ float coefs[64];
  __shared__ bf16 As[64 * 64];
  __shared__ bf16 Us[64 * 64];
  __shared__ bf16 Ss[64 * 64];

  int tid = threadIdx.x;
  if (tid < 64) {
    int rr = tid < nrows ? tid : nrows - 1;
    toks[tid] = tl[rr];
    coefs[tid] = tid < nrows ? wlp[tid] : 0.0f;
  }
  __syncthreads();

  int lane = tid & 63, wv = tid >> 6;
  int srow = tid >> 3, scol = (tid & 7) * 8;
  int fr = lane & 15, fk = (lane >> 4) * 8;
  size_t tokA0 = (size_t)toks[srow] * D_DIM;
  size_t tokA1 = (size_t)toks[32 + srow] * D_DIM;
  const bf16* Ue = Ub + (size_t)e * RK * D_DIM;
  f32x4 acc1[4] = {};

  for (int k0 = 0; k0 < D_DIM; k0 += 64) {
    __syncthreads();
    gload16(encb + tokA0 + k0 + scol, &As[srow * 64 + scol]);
    gload16(encb + tokA1 + k0 + scol, &As[(32 + srow) * 64 + scol]);
    gload16(Ue + (size_t)srow * D_DIM + k0 + scol, &Us[srow * 64 + scol]);
    gload16(Ue + (size_t)(32 + srow) * D_DIM + k0 + scol, &Us[(32 + srow) * 64 + scol]);
    __syncthreads();
#pragma unroll
    for (int kk = 0; kk < 2; ++kk) {
      bf16x8 af = *(const bf16x8*)&As[(wv * 16 + fr) * 64 + kk * 32 + fk];
#pragma unroll
      for (int n = 0; n < 4; ++n) {
        bf16x8 bv = *(const bf16x8*)&Us[(n * 16 + fr) * 64 + kk * 32 + fk];
        acc1[n] = __builtin_amdgcn_mfma_f32_16x16x32_bf16(af, bv, acc1[n], 0, 0, 0);
      }
    }
  }
  int rg = (lane >> 4) * 4;
#pragma unroll
  for (int n = 0; n < 4; ++n)
#pragma unroll
    for (int r = 0; r < 4; ++r) {
      int row = wv * 16 + rg + r;
      float v = acc1[n][r];
      float s = v / (1.0f + __expf(-v));
      Ss[row * 64 + n * 16 + fr] = (bf16)(s * coefs[row]);
    }
  __syncthreads();
  bf16x8 a2[4][2];
#pragma unroll
  for (int m = 0; m < 4; ++m)
#pragma unroll
    for (int kk = 0; kk < 2; ++kk)
      a2[m][kk] = *(const bf16x8*)&Ss[(m * 16 + fr) * 64 + kk * 32 + fk];
  const bf16* Ve = Vb + (size_t)e * D_DIM * RK;
  int colbase = wv * 256;
  for (int nj = 0; nj < 16; ++nj) {
    int dcol = colbase + nj * 16 + fr;
    bf16x8 b0 = *(const bf16x8*)&Ve[(size_t)dcol * RK + fk];
    bf16x8 b1 = *(const bf16x8*)&Ve[(size_t)dcol * RK + 32 + fk];
#pragma unroll
    for (int m = 0; m < 4; ++m) {
      f32x4 a = {};
      a = __builtin_amdgcn_mfma_f32_16x16x32_bf16(a2[m][0], b0, a, 0, 0, 0);
      a = __builtin_amdgcn_mfma_f32_16x16x32_bf16(a2[m][1], b1, a, 0, 0, 0);
#pragma unroll
      for (int r = 0; r < 4; ++r) {
        int row = m * 16 + rg + r;
        if (row < nrows) {
          size_t off = (size_t)toks[row] * D_DIM + dcol;
          out[off] += a[r];
        }
      }
    }
  }
}

extern "C" void kernel_launch(void* const* d_in, const int* in_sizes, int n_in,
                              void* d_out, int out_size, void* d_ws, size_t ws_size,
                              hipStream_t stream) {
  const float* x   = (const float*)d_in[0];
  const float* We  = (const float*)d_in[1];
  const float* be  = (const float*)d_in[2];
  const float* Wg  = (const float*)d_in[3];
  const float* U   = (const float*)d_in[4];
  const float* V   = (const float*)d_in[5];
  const float* gam = (const float*)d_in[6];
  float* out = (float*)d_out;
  char* ws = (char*)d_ws;

  int*   cnt  = (int*)(ws + 0);                       // 128 B   (zeroed)
  float* Gt   = (float*)(ws + 256);                   // 64 KiB  (zeroed), [d][e]
  float* bg   = (float*)(ws + 66048);                 // 64 B
  bf16*  xb   = (bf16*)(ws + 131072);                 // 32 MiB
  bf16*  encb = (bf16*)(ws + 131072 + 33554432);      // 32 MiB
  bf16*  Wb   = (bf16*)(ws + 131072 + 2 * 33554432);  // 2 MiB
  bf16*  Ubf  = (bf16*)(ws + 131072 + 2 * 33554432 + 2097152);
  bf16*  Vbf  = (bf16*)(ws + 131072 + 2 * 33554432 + 2 * 2097152);
  int*   lists= (int*)(ws + 131072 + 2 * 33554432 + 3 * 2097152);
  float* wl   = (float*)(ws + 131072 + 2 * 33554432 + 4 * 2097152);

  hipMemsetAsync(ws, 0, 66048, stream);

  k_cast<<<1024, 256, 0, stream>>>(We, Wb, 1048576 / 4);
  k_cast<<<1024, 256, 0, stream>>>(U, Ubf, 1048576 / 4);
  k_cast<<<1024, 256, 0, stream>>>(V, Vbf, 1048576 / 4);

  dim3 gg(4, 16, 8);
  k_gmat<<<gg, 256, 0, stream>>>(Wg, We, Gt);
  k_bgate<<<16, 256, 0, stream>>>(Wg, be, bg);

  k_gatecast<<<2048, 256, 0, stream>>>(x, Gt, bg, gam, xb, cnt, lists, wl);

  dim3 ge(8, 128);
  k_encgemm<<<ge, 256, 0, stream>>>(xb, Wb, be, out, encb);

  dim3 gx(16, 256);
  k_expert<<<gx, 256, 0, stream>>>(encb, Ubf, Vbf, cnt, lists, wl, out, 0);
  k_expert<<<gx, 256, 0, stream>>>(encb, Ubf, Vbf, cnt, lists, wl, out, 1);
}

// Round 8
// 349.977 us; speedup vs baseline: 1.5897x; 1.2118x over previous
//
#include <hip/hip_runtime.h>
#include <hip/hip_bf16.h>

#define D_DIM 1024
#define NE 16
#define RK 64
#define NTOK 16384

typedef __bf16 bf16;
typedef __bf16 bf16x8 __attribute__((ext_vector_type(8)));
typedef __bf16 bf16x4 __attribute__((ext_vector_type(4)));
typedef float f32x4 __attribute__((ext_vector_type(4)));

__device__ __forceinline__ void gload16(const void* g, void* l) {
  __builtin_amdgcn_global_load_lds((const __attribute__((address_space(1))) unsigned int*)g,
                                   (__attribute__((address_space(3))) unsigned int*)l,
                                   16, 0, 0);
}

// ---------------- casts (weights only) ----------------
__global__ void k_cast(const float* __restrict__ s, bf16* __restrict__ d, int n4) {
  int i = blockIdx.x * blockDim.x + threadIdx.x;
  if (i >= n4) return;
  float4 v = ((const float4*)s)[i];
  bf16x4 o = { (bf16)v.x, (bf16)v.y, (bf16)v.z, (bf16)v.w };
  ((bf16x4*)d)[i] = o;
}

// ---------------- Gt = (W_gate @ W_enc)^T stored [d][e]  (fp64 partials, atomic) ----------------
__global__ void k_gmat(const float* __restrict__ Wg, const float* __restrict__ We,
                       float* __restrict__ Gt) {
  int d = blockIdx.x * 256 + threadIdx.x;
  int e = blockIdx.y;
  int j0 = blockIdx.z * 128;
  double a0 = 0.0, a1 = 0.0, a2 = 0.0, a3 = 0.0;
  for (int j = j0; j < j0 + 128; j += 4) {
    a0 += (double)Wg[e * D_DIM + j + 0] * (double)We[(size_t)(j + 0) * D_DIM + d];
    a1 += (double)Wg[e * D_DIM + j + 1] * (double)We[(size_t)(j + 1) * D_DIM + d];
    a2 += (double)Wg[e * D_DIM + j + 2] * (double)We[(size_t)(j + 2) * D_DIM + d];
    a3 += (double)Wg[e * D_DIM + j + 3] * (double)We[(size_t)(j + 3) * D_DIM + d];
  }
  atomicAdd(&Gt[d * NE + e], (float)((a0 + a1) + (a2 + a3)));
}

// ---------------- bgate[e] = W_gate[e,:] . b_enc ----------------
__global__ void k_bgate(const float* __restrict__ Wg, const float* __restrict__ be,
                        float* __restrict__ bg) {
  __shared__ double red[256];
  int e = blockIdx.x, t = threadIdx.x;
  double a = 0.0;
  for (int j = t; j < D_DIM; j += 256) a += (double)Wg[e * D_DIM + j] * (double)be[j];
  red[t] = a; __syncthreads();
  for (int s = 128; s > 0; s >>= 1) { if (t < s) red[t] += red[t + s]; __syncthreads(); }
  if (t == 0) bg[e] = (float)red[0];
}

// ---------------- fused gating + x->bf16 cast (R8: NO global atomics) ----------------
// R7 post-mortem: 32K same-line device-scope atomicAdd-with-return in the tail
// serialize globally (~150us floor that survived 3 load-pattern rewrites).
// R8: write per-token (packed expert ids, weight pair) densely; list build
// moves to k_scatter (block-aggregated counting sort, 16x fewer global atomics,
// amortized). Logit/selection/weight numerics identical to R7.
__global__ __launch_bounds__(256) void k_gatecast(const float* __restrict__ x,
                                                  const float* __restrict__ Gt,
                                                  const float* __restrict__ bg,
                                                  const float* __restrict__ gamma,
                                                  bf16* __restrict__ xb,
                                                  int* __restrict__ pk,
                                                  float2* __restrict__ wpair) {
  __shared__ float Ls[4 * 2 * NE];  // [wave][token][expert]
  int tid = threadIdx.x;
  int wv = tid >> 6, lane = tid & 63;
  int g = lane & 15;   // expert owned by this lane
  int s = lane >> 4;   // j-quad slice 0..3
  int tokbase = (blockIdx.x * 4 + wv) * 2;
  const float* xq = x + (size_t)tokbase * D_DIM + s * 4;
  const float* Gq = Gt + (size_t)(s * 4) * NE + g;   // + j0*NE per chunk

  float acc0 = 0.0f, acc1 = 0.0f;
  float gt0 = Gq[0 * NE], gt1 = Gq[1 * NE], gt2 = Gq[2 * NE], gt3 = Gq[3 * NE];
  float4 x0 = *(const float4*)xq;
  float4 x1 = *(const float4*)(xq + D_DIM);
  for (int j0 = 0; j0 < D_DIM; j0 += 16) {
    int jn = j0 + 16;
    int jp = (jn < D_DIM) ? jn : 0;  // last-iter prefetch clamped (discarded)
    const float* Gn = Gq + (size_t)jp * NE;
    float gn0 = Gn[0 * NE], gn1 = Gn[1 * NE], gn2 = Gn[2 * NE], gn3 = Gn[3 * NE];
    float4 xn0 = *(const float4*)(xq + jp);
    float4 xn1 = *(const float4*)(xq + D_DIM + jp);
    acc0 += x0.x * gt0 + x0.y * gt1 + x0.z * gt2 + x0.w * gt3;
    acc1 += x1.x * gt0 + x1.y * gt1 + x1.z * gt2 + x1.w * gt3;
    gt0 = gn0; gt1 = gn1; gt2 = gn2; gt3 = gn3;
    x0 = xn0; x1 = xn1;
  }
  acc0 += __shfl_xor(acc0, 16); acc0 += __shfl_xor(acc0, 32);
  acc1 += __shfl_xor(acc1, 16); acc1 += __shfl_xor(acc1, 32);
  if (s == 0) {
    Ls[wv * 32 + g] = acc0;
    Ls[wv * 32 + 16 + g] = acc1;
  }

  // tail cast: coalesced re-read (L1/L2-hot) + bf16x4 stores
#pragma unroll
  for (int t = 0; t < 2; ++t) {
    const float4* xrow = (const float4*)(x + (size_t)(tokbase + t) * D_DIM);
    bf16x4* orow = (bf16x4*)(xb + (size_t)(tokbase + t) * D_DIM);
#pragma unroll
    for (int r = 0; r < 4; ++r) {
      float4 v = xrow[lane + 64 * r];
      bf16x4 o = { (bf16)v.x, (bf16)v.y, (bf16)v.z, (bf16)v.w };
      orow[lane + 64 * r] = o;
    }
  }
  __syncthreads();

  if (lane < 2) {
    int t = lane;
    int tok = tokbase + t;
    const float* lrow = &Ls[wv * 32 + t * 16];
    float v1 = -1e30f, v2 = -1e30f; int i1 = 0, i2 = 0;
#pragma unroll
    for (int e = 0; e < NE; ++e) {
      float v = lrow[e] + bg[e];
      if (v > v1) { v2 = v1; i2 = i1; v1 = v; i1 = e; }
      else if (v > v2) { v2 = v; i2 = e; }
    }
    float e1 = expf(v2 - v1);
    float den = 1.0f + e1 + 1e-12f;
    float w0 = (1.0f / den) * gamma[i1];
    float w1 = (e1 / den) * gamma[i2];
    pk[tok] = i1 | (i2 << 8);
    wpair[tok] = make_float2(w0, w1);
  }
}

// ---------------- scatter: block-aggregated counting sort into per-bin lists ----------------
// 64 blocks x 256 tokens. LDS histogram -> 1 global atomicAdd per bin per
// block (<=2048 total, amortized over 256 tokens) -> LDS-ranked scatter.
// List order is schedule-dependent but per-token output is order-invariant.
__global__ __launch_bounds__(256) void k_scatter(const int* __restrict__ pk,
                                                 const float2* __restrict__ wpair,
                                                 int* __restrict__ cnt,
                                                 int* __restrict__ lists,
                                                 float* __restrict__ wl) {
  __shared__ int lc[32];    // block histogram
  __shared__ int base[32];  // block base within global bin
  __shared__ int lc2[32];   // scatter rank counters
  int tid = threadIdx.x;
  int tok = blockIdx.x * 256 + tid;
  if (tid < 32) { lc[tid] = 0; lc2[tid] = 0; }
  __syncthreads();
  int p = pk[tok];
  float2 w = wpair[tok];
  int b0 = p & 0xff;
  int b1 = 16 + ((p >> 8) & 0xff);
  atomicAdd(&lc[b0], 1);
  atomicAdd(&lc[b1], 1);
  __syncthreads();
  if (tid < 32 && lc[tid] > 0) base[tid] = atomicAdd(&cnt[tid], lc[tid]);
  __syncthreads();
  int r0 = base[b0] + atomicAdd(&lc2[b0], 1);
  lists[(size_t)b0 * NTOK + r0] = tok;
  wl[(size_t)b0 * NTOK + r0] = w.x;
  int r1 = base[b1] + atomicAdd(&lc2[b1], 1);
  lists[(size_t)b1 * NTOK + r1] = tok;
  wl[(size_t)b1 * NTOK + r1] = w.y;
}

// ---------------- encoder GEMM: out = x @ W_enc^T + b (fp32) ; encb = bf16(out) ----------------
__global__ __launch_bounds__(256) void k_encgemm(const bf16* __restrict__ A,
                                                 const bf16* __restrict__ W,
                                                 const float* __restrict__ bias,
                                                 float* __restrict__ out,
                                                 bf16* __restrict__ encb) {
  __shared__ bf16 As[128 * 64];
  __shared__ bf16 Bs[128 * 64];
  const int K = D_DIM;
  int tid = threadIdx.x;
  int bn = blockIdx.x * 128;
  int bm = blockIdx.y * 128;
  int lane = tid & 63, wv = tid >> 6;
  int wm = (wv >> 1) * 64, wn = (wv & 1) * 64;
  int srow = tid >> 3, scol = (tid & 7) * 8;
  int fr = lane & 15, fk = (lane >> 4) * 8;
  f32x4 acc[4][4] = {};
  for (int k0 = 0; k0 < K; k0 += 64) {
    __syncthreads();
#pragma unroll
    for (int p = 0; p < 4; ++p) {
      int r = p * 32 + srow;
      gload16(A + (size_t)(bm + r) * K + k0 + scol, &As[r * 64 + scol]);
    }
#pragma unroll
    for (int p = 0; p < 4; ++p) {
      int r = p * 32 + srow;
      gload16(W + (size_t)(bn + r) * K + k0 + scol, &Bs[r * 64 + scol]);
    }
    __syncthreads();
#pragma unroll
    for (int kk = 0; kk < 2; ++kk) {
      bf16x8 af[4], bv[4];
#pragma unroll
      for (int m = 0; m < 4; ++m)
        af[m] = *(const bf16x8*)&As[(wm + m * 16 + fr) * 64 + kk * 32 + fk];
#pragma unroll
      for (int n = 0; n < 4; ++n)
        bv[n] = *(const bf16x8*)&Bs[(wn + n * 16 + fr) * 64 + kk * 32 + fk];
#pragma unroll
      for (int m = 0; m < 4; ++m)
#pragma unroll
        for (int n = 0; n < 4; ++n)
          acc[m][n] = __builtin_amdgcn_mfma_f32_16x16x32_bf16(af[m], bv[n], acc[m][n], 0, 0, 0);
    }
  }
  int rg = (lane >> 4) * 4;
#pragma unroll
  for (int n = 0; n < 4; ++n) {
    int col = bn + wn + n * 16 + fr;
    float bval = bias[col];
#pragma unroll
    for (int m = 0; m < 4; ++m) {
#pragma unroll
      for (int r = 0; r < 4; ++r) {
        int row = bm + wm + m * 16 + rg + r;
        float v = acc[m][n][r] + bval;
        out[(size_t)row * D_DIM + col] = v;
        encb[(size_t)row * D_DIM + col] = (bf16)v;
      }
    }
  }
}

// ---------------- expert kernel (one slot): gather 64 tokens, S=silu(enc U^T)*coef, out += S V^T ----------------
__global__ __launch_bounds__(256) void k_expert(const bf16* __restrict__ encb,
                                                const bf16* __restrict__ Ub,
                                                const bf16* __restrict__ Vb,
                                                const int* __restrict__ cnt,
                                                const int* __restrict__ lists,
                                                const float* __restrict__ wl,
                                                float* __restrict__ out, int slot) {
  int e = blockIdx.x;
  int c = cnt[slot * NE + e];
  int t0 = blockIdx.y * 64;
  if (t0 >= c) return;
  int nrows = c - t0; if (nrows > 64) nrows = 64;
  const int* tl = lists + (size_t)(slot * NE + e) * NTOK + t0;
  const float* wlp = wl + (size_t)(slot * NE + e) * NTOK + t0;

  __shared__ int toks[64];
  __shared__ float coefs[64];
  __shared__ bf16 As[64 * 64];
  __shared__ bf16 Us[64 * 64];
  __shared__ bf16 Ss[64 * 64];

  int tid = threadIdx.x;
  if (tid < 64) {
    int rr = tid < nrows ? tid : nrows - 1;
    toks[tid] = tl[rr];
    coefs[tid] = tid < nrows ? wlp[tid] : 0.0f;
  }
  __syncthreads();

  int lane = tid & 63, wv = tid >> 6;
  int srow = tid >> 3, scol = (tid & 7) * 8;
  int fr = lane & 15, fk = (lane >> 4) * 8;
  size_t tokA0 = (size_t)toks[srow] * D_DIM;
  size_t tokA1 = (size_t)toks[32 + srow] * D_DIM;
  const bf16* Ue = Ub + (size_t)e * RK * D_DIM;
  f32x4 acc1[4] = {};

  for (int k0 = 0; k0 < D_DIM; k0 += 64) {
    __syncthreads();
    gload16(encb + tokA0 + k0 + scol, &As[srow * 64 + scol]);
    gload16(encb + tokA1 + k0 + scol, &As[(32 + srow) * 64 + scol]);
    gload16(Ue + (size_t)srow * D_DIM + k0 + scol, &Us[srow * 64 + scol]);
    gload16(Ue + (size_t)(32 + srow) * D_DIM + k0 + scol, &Us[(32 + srow) * 64 + scol]);
    __syncthreads();
#pragma unroll
    for (int kk = 0; kk < 2; ++kk) {
      bf16x8 af = *(const bf16x8*)&As[(wv * 16 + fr) * 64 + kk * 32 + fk];
#pragma unroll
      for (int n = 0; n < 4; ++n) {
        bf16x8 bv = *(const bf16x8*)&Us[(n * 16 + fr) * 64 + kk * 32 + fk];
        acc1[n] = __builtin_amdgcn_mfma_f32_16x16x32_bf16(af, bv, acc1[n], 0, 0, 0);
      }
    }
  }
  int rg = (lane >> 4) * 4;
#pragma unroll
  for (int n = 0; n < 4; ++n)
#pragma unroll
    for (int r = 0; r < 4; ++r) {
      int row = wv * 16 + rg + r;
      float v = acc1[n][r];
      float s = v / (1.0f + __expf(-v));
      Ss[row * 64 + n * 16 + fr] = (bf16)(s * coefs[row]);
    }
  __syncthreads();
  bf16x8 a2[4][2];
#pragma unroll
  for (int m = 0; m < 4; ++m)
#pragma unroll
    for (int kk = 0; kk < 2; ++kk)
      a2[m][kk] = *(const bf16x8*)&Ss[(m * 16 + fr) * 64 + kk * 32 + fk];
  const bf16* Ve = Vb + (size_t)e * D_DIM * RK;
  int colbase = wv * 256;
  for (int nj = 0; nj < 16; ++nj) {
    int dcol = colbase + nj * 16 + fr;
    bf16x8 b0 = *(const bf16x8*)&Ve[(size_t)dcol * RK + fk];
    bf16x8 b1 = *(const bf16x8*)&Ve[(size_t)dcol * RK + 32 + fk];
#pragma unroll
    for (int m = 0; m < 4; ++m) {
      f32x4 a = {};
      a = __builtin_amdgcn_mfma_f32_16x16x32_bf16(a2[m][0], b0, a, 0, 0, 0);
      a = __builtin_amdgcn_mfma_f32_16x16x32_bf16(a2[m][1], b1, a, 0, 0, 0);
#pragma unroll
      for (int r = 0; r < 4; ++r) {
        int row = m * 16 + rg + r;
        if (row < nrows) {
          size_t off = (size_t)toks[row] * D_DIM + dcol;
          out[off] += a[r];
        }
      }
    }
  }
}

extern "C" void kernel_launch(void* const* d_in, const int* in_sizes, int n_in,
                              void* d_out, int out_size, void* d_ws, size_t ws_size,
                              hipStream_t stream) {
  const float* x   = (const float*)d_in[0];
  const float* We  = (const float*)d_in[1];
  const float* be  = (const float*)d_in[2];
  const float* Wg  = (const float*)d_in[3];
  const float* U   = (const float*)d_in[4];
  const float* V   = (const float*)d_in[5];
  const float* gam = (const float*)d_in[6];
  float* out = (float*)d_out;
  char* ws = (char*)d_ws;

  int*    cnt  = (int*)(ws + 0);                       // 128 B   (zeroed)
  float*  Gt   = (float*)(ws + 256);                   // 64 KiB  (zeroed), [d][e]
  float*  bg   = (float*)(ws + 66048);                 // 64 B
  bf16*   xb   = (bf16*)(ws + 131072);                 // 32 MiB
  bf16*   encb = (bf16*)(ws + 131072 + 33554432);      // 32 MiB
  char*   base = ws + 131072 + 2 * 33554432;
  bf16*   Wb   = (bf16*)(base);                        // 2 MiB
  bf16*   Ubf  = (bf16*)(base + 2097152);
  bf16*   Vbf  = (bf16*)(base + 2 * 2097152);
  int*    lists= (int*)(base + 3 * 2097152);           // 2 MiB
  float*  wl   = (float*)(base + 4 * 2097152);         // 2 MiB
  int*    pk   = (int*)(base + 5 * 2097152);           // 64 KiB
  float2* wpr  = (float2*)(base + 5 * 2097152 + 131072); // 128 KiB

  hipMemsetAsync(ws, 0, 66048, stream);

  k_cast<<<1024, 256, 0, stream>>>(We, Wb, 1048576 / 4);
  k_cast<<<1024, 256, 0, stream>>>(U, Ubf, 1048576 / 4);
  k_cast<<<1024, 256, 0, stream>>>(V, Vbf, 1048576 / 4);

  dim3 gg(4, 16, 8);
  k_gmat<<<gg, 256, 0, stream>>>(Wg, We, Gt);
  k_bgate<<<16, 256, 0, stream>>>(Wg, be, bg);

  k_gatecast<<<2048, 256, 0, stream>>>(x, Gt, bg, gam, xb, pk, wpr);
  k_scatter<<<64, 256, 0, stream>>>(pk, wpr, cnt, lists, wl);

  dim3 ge(8, 128);
  k_encgemm<<<ge, 256, 0, stream>>>(xb, Wb, be, out, encb);

  dim3 gx(16, 256);
  k_expert<<<gx, 256, 0, stream>>>(encb, Ubf, Vbf, cnt, lists, wl, out, 0);
  k_expert<<<gx, 256, 0, stream>>>(encb, Ubf, Vbf, cnt, lists, wl, out, 1);
}

// Round 9
// 243.067 us; speedup vs baseline: 2.2889x; 1.4398x over previous
//
#include <hip/hip_runtime.h>
#include <hip/hip_bf16.h>

#define D_DIM 1024
#define NE 16
#define RK 64
#define NTOK 16384

typedef __bf16 bf16;
typedef __bf16 bf16x8 __attribute__((ext_vector_type(8)));
typedef __bf16 bf16x4 __attribute__((ext_vector_type(4)));
typedef float f32x4 __attribute__((ext_vector_type(4)));

__device__ __forceinline__ void gload16(const void* g, void* l) {
  __builtin_amdgcn_global_load_lds((const __attribute__((address_space(1))) unsigned int*)g,
                                   (__attribute__((address_space(3))) unsigned int*)l,
                                   16, 0, 0);
}

// ---------------- casts (weights only) ----------------
__global__ void k_cast(const float* __restrict__ s, bf16* __restrict__ d, int n4) {
  int i = blockIdx.x * blockDim.x + threadIdx.x;
  if (i >= n4) return;
  float4 v = ((const float4*)s)[i];
  bf16x4 o = { (bf16)v.x, (bf16)v.y, (bf16)v.z, (bf16)v.w };
  ((bf16x4*)d)[i] = o;
}

// ---------------- V cast + relayout: V[e][d][r] -> Vb2[e][r/8][d][r%8] ----------------
// R9: makes PV B-operand loads 256B-contiguous per quarter-wave (was a
// 16-line/instr gather at stride RK*2=128B).
__global__ void k_castv(const float* __restrict__ V, bf16* __restrict__ Vb2) {
  int id = blockIdx.x * 256 + threadIdx.x;   // (e,rb,d), d fastest; 131072 total
  int d = id & 1023;
  int rb = (id >> 10) & 7;
  int e = id >> 13;
  const float* src = V + ((size_t)(e * 1024 + d)) * 64 + rb * 8;
  float4 v0 = *(const float4*)src;
  float4 v1 = *(const float4*)(src + 4);
  bf16x8 o = { (bf16)v0.x, (bf16)v0.y, (bf16)v0.z, (bf16)v0.w,
               (bf16)v1.x, (bf16)v1.y, (bf16)v1.z, (bf16)v1.w };
  *(bf16x8*)(Vb2 + (size_t)id * 8) = o;
}

// ---------------- Gt = (W_gate @ W_enc)^T stored [d][e]  (fp64 partials, atomic) ----------------
__global__ void k_gmat(const float* __restrict__ Wg, const float* __restrict__ We,
                       float* __restrict__ Gt) {
  int d = blockIdx.x * 256 + threadIdx.x;
  int e = blockIdx.y;
  int j0 = blockIdx.z * 128;
  double a0 = 0.0, a1 = 0.0, a2 = 0.0, a3 = 0.0;
  for (int j = j0; j < j0 + 128; j += 4) {
    a0 += (double)Wg[e * D_DIM + j + 0] * (double)We[(size_t)(j + 0) * D_DIM + d];
    a1 += (double)Wg[e * D_DIM + j + 1] * (double)We[(size_t)(j + 1) * D_DIM + d];
    a2 += (double)Wg[e * D_DIM + j + 2] * (double)We[(size_t)(j + 2) * D_DIM + d];
    a3 += (double)Wg[e * D_DIM + j + 3] * (double)We[(size_t)(j + 3) * D_DIM + d];
  }
  atomicAdd(&Gt[d * NE + e], (float)((a0 + a1) + (a2 + a3)));
}

// ---------------- bgate[e] = W_gate[e,:] . b_enc ----------------
__global__ void k_bgate(const float* __restrict__ Wg, const float* __restrict__ be,
                        float* __restrict__ bg) {
  __shared__ double red[256];
  int e = blockIdx.x, t = threadIdx.x;
  double a = 0.0;
  for (int j = t; j < D_DIM; j += 256) a += (double)Wg[e * D_DIM + j] * (double)be[j];
  red[t] = a; __syncthreads();
  for (int s = 128; s > 0; s >>= 1) { if (t < s) red[t] += red[t + s]; __syncthreads(); }
  if (t == 0) bg[e] = (float)red[0];
}

// ---------------- fused gating + x->bf16 cast (no global atomics) ----------------
__global__ __launch_bounds__(256) void k_gatecast(const float* __restrict__ x,
                                                  const float* __restrict__ Gt,
                                                  const float* __restrict__ bg,
                                                  const float* __restrict__ gamma,
                                                  bf16* __restrict__ xb,
                                                  int* __restrict__ pk,
                                                  float2* __restrict__ wpair) {
  __shared__ float Ls[4 * 2 * NE];  // [wave][token][expert]
  int tid = threadIdx.x;
  int wv = tid >> 6, lane = tid & 63;
  int g = lane & 15;
  int s = lane >> 4;
  int tokbase = (blockIdx.x * 4 + wv) * 2;
  const float* xq = x + (size_t)tokbase * D_DIM + s * 4;
  const float* Gq = Gt + (size_t)(s * 4) * NE + g;

  float acc0 = 0.0f, acc1 = 0.0f;
  float gt0 = Gq[0 * NE], gt1 = Gq[1 * NE], gt2 = Gq[2 * NE], gt3 = Gq[3 * NE];
  float4 x0 = *(const float4*)xq;
  float4 x1 = *(const float4*)(xq + D_DIM);
  for (int j0 = 0; j0 < D_DIM; j0 += 16) {
    int jn = j0 + 16;
    int jp = (jn < D_DIM) ? jn : 0;
    const float* Gn = Gq + (size_t)jp * NE;
    float gn0 = Gn[0 * NE], gn1 = Gn[1 * NE], gn2 = Gn[2 * NE], gn3 = Gn[3 * NE];
    float4 xn0 = *(const float4*)(xq + jp);
    float4 xn1 = *(const float4*)(xq + D_DIM + jp);
    acc0 += x0.x * gt0 + x0.y * gt1 + x0.z * gt2 + x0.w * gt3;
    acc1 += x1.x * gt0 + x1.y * gt1 + x1.z * gt2 + x1.w * gt3;
    gt0 = gn0; gt1 = gn1; gt2 = gn2; gt3 = gn3;
    x0 = xn0; x1 = xn1;
  }
  acc0 += __shfl_xor(acc0, 16); acc0 += __shfl_xor(acc0, 32);
  acc1 += __shfl_xor(acc1, 16); acc1 += __shfl_xor(acc1, 32);
  if (s == 0) {
    Ls[wv * 32 + g] = acc0;
    Ls[wv * 32 + 16 + g] = acc1;
  }

#pragma unroll
  for (int t = 0; t < 2; ++t) {
    const float4* xrow = (const float4*)(x + (size_t)(tokbase + t) * D_DIM);
    bf16x4* orow = (bf16x4*)(xb + (size_t)(tokbase + t) * D_DIM);
#pragma unroll
    for (int r = 0; r < 4; ++r) {
      float4 v = xrow[lane + 64 * r];
      bf16x4 o = { (bf16)v.x, (bf16)v.y, (bf16)v.z, (bf16)v.w };
      orow[lane + 64 * r] = o;
    }
  }
  __syncthreads();

  if (lane < 2) {
    int t = lane;
    int tok = tokbase + t;
    const float* lrow = &Ls[wv * 32 + t * 16];
    float v1 = -1e30f, v2 = -1e30f; int i1 = 0, i2 = 0;
#pragma unroll
    for (int e = 0; e < NE; ++e) {
      float v = lrow[e] + bg[e];
      if (v > v1) { v2 = v1; i2 = i1; v1 = v; i1 = e; }
      else if (v > v2) { v2 = v; i2 = e; }
    }
    float e1 = expf(v2 - v1);
    float den = 1.0f + e1 + 1e-12f;
    float w0 = (1.0f / den) * gamma[i1];
    float w1 = (e1 / den) * gamma[i2];
    pk[tok] = i1 | (i2 << 8);
    wpair[tok] = make_float2(w0, w1);
  }
}

// ---------------- scatter: block-aggregated counting sort into per-bin lists ----------------
__global__ __launch_bounds__(256) void k_scatter(const int* __restrict__ pk,
                                                 const float2* __restrict__ wpair,
                                                 int* __restrict__ cnt,
                                                 int* __restrict__ lists,
                                                 float* __restrict__ wl) {
  __shared__ int lc[32];
  __shared__ int base[32];
  __shared__ int lc2[32];
  int tid = threadIdx.x;
  int tok = blockIdx.x * 256 + tid;
  if (tid < 32) { lc[tid] = 0; lc2[tid] = 0; }
  __syncthreads();
  int p = pk[tok];
  float2 w = wpair[tok];
  int b0 = p & 0xff;
  int b1 = 16 + ((p >> 8) & 0xff);
  atomicAdd(&lc[b0], 1);
  atomicAdd(&lc[b1], 1);
  __syncthreads();
  if (tid < 32 && lc[tid] > 0) base[tid] = atomicAdd(&cnt[tid], lc[tid]);
  __syncthreads();
  int r0 = base[b0] + atomicAdd(&lc2[b0], 1);
  lists[(size_t)b0 * NTOK + r0] = tok;
  wl[(size_t)b0 * NTOK + r0] = w.x;
  int r1 = base[b1] + atomicAdd(&lc2[b1], 1);
  lists[(size_t)b1 * NTOK + r1] = tok;
  wl[(size_t)b1 * NTOK + r1] = w.y;
}

// ---------------- block table: compact (bin, t0) list, one wave ----------------
__global__ void k_btab(const int* __restrict__ cnt, int2* __restrict__ btab,
                       int* __restrict__ nblk) {
  int lane = threadIdx.x;
  int nb = (lane < 32) ? ((cnt[lane] + 63) >> 6) : 0;
  int pfx = nb;
  for (int off = 1; off < 32; off <<= 1) {
    int v = __shfl_up(pfx, off);
    if (lane >= off) pfx += v;
  }
  int start = pfx - nb;
  if (lane < 32) {
    int c = cnt[lane];
    int i = 0;
    for (int t0 = 0; t0 < c; t0 += 64, ++i)
      btab[start + i] = make_int2(lane, t0);
  }
  if (lane == 31) *nblk = pfx;
}

// ---------------- encoder GEMM: out = x @ W_enc^T + b (fp32) ; encb = bf16(out) ----------------
__global__ __launch_bounds__(256) void k_encgemm(const bf16* __restrict__ A,
                                                 const bf16* __restrict__ W,
                                                 const float* __restrict__ bias,
                                                 float* __restrict__ out,
                                                 bf16* __restrict__ encb) {
  __shared__ bf16 As[128 * 64];
  __shared__ bf16 Bs[128 * 64];
  const int K = D_DIM;
  int tid = threadIdx.x;
  int bn = blockIdx.x * 128;
  int bm = blockIdx.y * 128;
  int lane = tid & 63, wv = tid >> 6;
  int wm = (wv >> 1) * 64, wn = (wv & 1) * 64;
  int srow = tid >> 3, scol = (tid & 7) * 8;
  int fr = lane & 15, fk = (lane >> 4) * 8;
  f32x4 acc[4][4] = {};
  for (int k0 = 0; k0 < K; k0 += 64) {
    __syncthreads();
#pragma unroll
    for (int p = 0; p < 4; ++p) {
      int r = p * 32 + srow;
      gload16(A + (size_t)(bm + r) * K + k0 + scol, &As[r * 64 + scol]);
    }
#pragma unroll
    for (int p = 0; p < 4; ++p) {
      int r = p * 32 + srow;
      gload16(W + (size_t)(bn + r) * K + k0 + scol, &Bs[r * 64 + scol]);
    }
    __syncthreads();
#pragma unroll
    for (int kk = 0; kk < 2; ++kk) {
      bf16x8 af[4], bv[4];
#pragma unroll
      for (int m = 0; m < 4; ++m)
        af[m] = *(const bf16x8*)&As[(wm + m * 16 + fr) * 64 + kk * 32 + fk];
#pragma unroll
      for (int n = 0; n < 4; ++n)
        bv[n] = *(const bf16x8*)&Bs[(wn + n * 16 + fr) * 64 + kk * 32 + fk];
#pragma unroll
      for (int m = 0; m < 4; ++m)
#pragma unroll
        for (int n = 0; n < 4; ++n)
          acc[m][n] = __builtin_amdgcn_mfma_f32_16x16x32_bf16(af[m], bv[n], acc[m][n], 0, 0, 0);
    }
  }
  int rg = (lane >> 4) * 4;
#pragma unroll
  for (int n = 0; n < 4; ++n) {
    int col = bn + wn + n * 16 + fr;
    float bval = bias[col];
#pragma unroll
    for (int m = 0; m < 4; ++m) {
#pragma unroll
      for (int r = 0; r < 4; ++r) {
        int row = bm + wm + m * 16 + rg + r;
        float v = acc[m][n][r] + bval;
        out[(size_t)row * D_DIM + col] = v;
        encb[(size_t)row * D_DIM + col] = (bf16)v;
      }
    }
  }
}

// ---------------- expert kernel (merged slots): S=silu(enc U^T)*coef -> delta = S V^T ----------------
// R9: both slots in one dispatch (no out RMW -> no race). Writes bf16 delta
// to dense per-slot buffers (each (slot,tok,col) written exactly once).
// Compact grid via btab. V loads coalesced via Vb2 layout.
__global__ __launch_bounds__(256) void k_expert(const bf16* __restrict__ encb,
                                                const bf16* __restrict__ Ub,
                                                const bf16* __restrict__ Vb2,
                                                const int* __restrict__ cnt,
                                                const int* __restrict__ lists,
                                                const float* __restrict__ wl,
                                                const int2* __restrict__ btab,
                                                const int* __restrict__ nblk,
                                                bf16* __restrict__ d0,
                                                bf16* __restrict__ d1) {
  int bid = blockIdx.x;
  if (bid >= *nblk) return;
  int2 bt = btab[bid];
  int bin = bt.x, t0 = bt.y;
  int slot = bin >> 4, e = bin & 15;
  int c = cnt[bin];
  int nrows = c - t0; if (nrows > 64) nrows = 64;
  const int* tl = lists + (size_t)bin * NTOK + t0;
  const float* wlp = wl + (size_t)bin * NTOK + t0;

  __shared__ int toks[64];
  __shared__ float coefs[64];
  __shared__ bf16 As[64 * 64];
  __shared__ bf16 Us[64 * 64];
  __shared__ bf16 Ss[64 * 64];

  int tid = threadIdx.x;
  if (tid < 64) {
    int rr = tid < nrows ? tid : nrows - 1;
    toks[tid] = tl[rr];
    coefs[tid] = tid < nrows ? wlp[tid] : 0.0f;
  }
  __syncthreads();

  int lane = tid & 63, wv = tid >> 6;
  int srow = tid >> 3, scol = (tid & 7) * 8;
  int fr = lane & 15, fk = (lane >> 4) * 8;
  size_t tokA0 = (size_t)toks[srow] * D_DIM;
  size_t tokA1 = (size_t)toks[32 + srow] * D_DIM;
  const bf16* Ue = Ub + (size_t)e * RK * D_DIM;
  f32x4 acc1[4] = {};

  for (int k0 = 0; k0 < D_DIM; k0 += 64) {
    __syncthreads();
    gload16(encb + tokA0 + k0 + scol, &As[srow * 64 + scol]);
    gload16(encb + tokA1 + k0 + scol, &As[(32 + srow) * 64 + scol]);
    gload16(Ue + (size_t)srow * D_DIM + k0 + scol, &Us[srow * 64 + scol]);
    gload16(Ue + (size_t)(32 + srow) * D_DIM + k0 + scol, &Us[(32 + srow) * 64 + scol]);
    __syncthreads();
#pragma unroll
    for (int kk = 0; kk < 2; ++kk) {
      bf16x8 af = *(const bf16x8*)&As[(wv * 16 + fr) * 64 + kk * 32 + fk];
#pragma unroll
      for (int n = 0; n < 4; ++n) {
        bf16x8 bv = *(const bf16x8*)&Us[(n * 16 + fr) * 64 + kk * 32 + fk];
        acc1[n] = __builtin_amdgcn_mfma_f32_16x16x32_bf16(af, bv, acc1[n], 0, 0, 0);
      }
    }
  }
  int rg = (lane >> 4) * 4;
#pragma unroll
  for (int n = 0; n < 4; ++n)
#pragma unroll
    for (int r = 0; r < 4; ++r) {
      int row = wv * 16 + rg + r;
      float v = acc1[n][r];
      float s = v / (1.0f + __expf(-v));
      Ss[row * 64 + n * 16 + fr] = (bf16)(s * coefs[row]);
    }
  __syncthreads();
  bf16x8 a2[4][2];
#pragma unroll
  for (int m = 0; m < 4; ++m)
#pragma unroll
    for (int kk = 0; kk < 2; ++kk)
      a2[m][kk] = *(const bf16x8*)&Ss[(m * 16 + fr) * 64 + kk * 32 + fk];

  const bf16* Ve2 = Vb2 + (size_t)e * RK * D_DIM;  // [rb][d][8]
  bf16* dst = slot ? d1 : d0;
  int rb0 = lane >> 4;         // fk/8
  int colbase = wv * 256;
  for (int nj = 0; nj < 16; ++nj) {
    int dcol = colbase + nj * 16 + fr;
    bf16x8 b0 = *(const bf16x8*)&Ve2[((size_t)rb0 * D_DIM + dcol) * 8];
    bf16x8 b1 = *(const bf16x8*)&Ve2[((size_t)(rb0 + 4) * D_DIM + dcol) * 8];
#pragma unroll
    for (int m = 0; m < 4; ++m) {
      f32x4 a = {};
      a = __builtin_amdgcn_mfma_f32_16x16x32_bf16(a2[m][0], b0, a, 0, 0, 0);
      a = __builtin_amdgcn_mfma_f32_16x16x32_bf16(a2[m][1], b1, a, 0, 0, 0);
#pragma unroll
      for (int r = 0; r < 4; ++r) {
        int row = m * 16 + rg + r;
        if (row < nrows) {
          dst[(size_t)toks[row] * D_DIM + dcol] = (bf16)a[r];
        }
      }
    }
  }
}

// ---------------- final: out = enc(in out) + d0 + d1 ----------------
__global__ __launch_bounds__(256) void k_final(float* __restrict__ out,
                                               const bf16* __restrict__ d0,
                                               const bf16* __restrict__ d1) {
  size_t i = ((size_t)blockIdx.x * 256 + threadIdx.x) * 8;
  float4 o0 = *(float4*)(out + i);
  float4 o1 = *(float4*)(out + i + 4);
  bf16x8 a = *(const bf16x8*)(d0 + i);
  bf16x8 b = *(const bf16x8*)(d1 + i);
  o0.x += (float)a[0] + (float)b[0];
  o0.y += (float)a[1] + (float)b[1];
  o0.z += (float)a[2] + (float)b[2];
  o0.w += (float)a[3] + (float)b[3];
  o1.x += (float)a[4] + (float)b[4];
  o1.y += (float)a[5] + (float)b[5];
  o1.z += (float)a[6] + (float)b[6];
  o1.w += (float)a[7] + (float)b[7];
  *(float4*)(out + i) = o0;
  *(float4*)(out + i + 4) = o1;
}

extern "C" void kernel_launch(void* const* d_in, const int* in_sizes, int n_in,
                              void* d_out, int out_size, void* d_ws, size_t ws_size,
                              hipStream_t stream) {
  const float* x   = (const float*)d_in[0];
  const float* We  = (const float*)d_in[1];
  const float* be  = (const float*)d_in[2];
  const float* Wg  = (const float*)d_in[3];
  const float* U   = (const float*)d_in[4];
  const float* V   = (const float*)d_in[5];
  const float* gam = (const float*)d_in[6];
  float* out = (float*)d_out;
  char* ws = (char*)d_ws;

  int*    cnt  = (int*)(ws + 0);                       // 128 B   (zeroed)
  float*  Gt   = (float*)(ws + 256);                   // 64 KiB  (zeroed), [d][e]
  float*  bg   = (float*)(ws + 66048);                 // 64 B
  int2*   btab = (int2*)(ws + 66176);                  // 4.25 KiB
  int*    nblk = (int*)(ws + 70656);                   // 4 B
  bf16*   xb   = (bf16*)(ws + 131072);                 // 32 MiB (aliased: d0 after encgemm)
  bf16*   d0   = (bf16*)(ws + 131072);                 //   alias of xb (xb consumed by encgemm)
  bf16*   encb = (bf16*)(ws + 131072 + 33554432);      // 32 MiB
  char*   base = ws + 131072 + 2 * 33554432;
  bf16*   Wb   = (bf16*)(base);                        // 2 MiB
  bf16*   Ubf  = (bf16*)(base + 2097152);              // 2 MiB
  bf16*   Vb2  = (bf16*)(base + 2 * 2097152);          // 2 MiB  [e][r/8][d][8]
  int*    lists= (int*)(base + 3 * 2097152);           // 2 MiB
  float*  wl   = (float*)(base + 4 * 2097152);         // 2 MiB
  int*    pk   = (int*)(base + 5 * 2097152);           // 64 KiB
  float2* wpr  = (float2*)(base + 5 * 2097152 + 131072); // 128 KiB
  bf16*   d1   = (bf16*)(base + 5 * 2097152 + 131072 + 131072 + 131072); // 32 MiB

  hipMemsetAsync(ws, 0, 66048, stream);

  k_cast<<<1024, 256, 0, stream>>>(We, Wb, 1048576 / 4);
  k_cast<<<1024, 256, 0, stream>>>(U, Ubf, 1048576 / 4);
  k_castv<<<512, 256, 0, stream>>>(V, Vb2);

  dim3 gg(4, 16, 8);
  k_gmat<<<gg, 256, 0, stream>>>(Wg, We, Gt);
  k_bgate<<<16, 256, 0, stream>>>(Wg, be, bg);

  k_gatecast<<<2048, 256, 0, stream>>>(x, Gt, bg, gam, xb, pk, wpr);
  k_scatter<<<64, 256, 0, stream>>>(pk, wpr, cnt, lists, wl);
  k_btab<<<1, 64, 0, stream>>>(cnt, btab, nblk);

  dim3 ge(8, 128);
  k_encgemm<<<ge, 256, 0, stream>>>(xb, Wb, be, out, encb);

  k_expert<<<544, 256, 0, stream>>>(encb, Ubf, Vb2, cnt, lists, wl, btab, nblk, d0, d1);
  k_final<<<8192, 256, 0, stream>>>(out, d0, d1);
}

// Round 10
// 206.572 us; speedup vs baseline: 2.6933x; 1.1767x over previous
//
#include <hip/hip_runtime.h>
#include <hip/hip_bf16.h>

#define D_DIM 1024
#define NE 16
#define RK 64
#define NTOK 16384

typedef __bf16 bf16;
typedef __bf16 bf16x8 __attribute__((ext_vector_type(8)));
typedef __bf16 bf16x4 __attribute__((ext_vector_type(4)));
typedef float f32x4 __attribute__((ext_vector_type(4)));

__device__ __forceinline__ void gload16(const void* g, void* l) {
  __builtin_amdgcn_global_load_lds((const __attribute__((address_space(1))) unsigned int*)g,
                                   (__attribute__((address_space(3))) unsigned int*)l,
                                   16, 0, 0);
}

// ---------------- casts (weights only) ----------------
__global__ void k_cast(const float* __restrict__ s, bf16* __restrict__ d, int n4) {
  int i = blockIdx.x * blockDim.x + threadIdx.x;
  if (i >= n4) return;
  float4 v = ((const float4*)s)[i];
  bf16x4 o = { (bf16)v.x, (bf16)v.y, (bf16)v.z, (bf16)v.w };
  ((bf16x4*)d)[i] = o;
}

// ---------------- V cast + relayout: V[e][d][r] -> Vb2[e][r/8][d][r%8] ----------------
__global__ void k_castv(const float* __restrict__ V, bf16* __restrict__ Vb2) {
  int id = blockIdx.x * 256 + threadIdx.x;
  int d = id & 1023;
  int rb = (id >> 10) & 7;
  int e = id >> 13;
  const float* src = V + ((size_t)(e * 1024 + d)) * 64 + rb * 8;
  float4 v0 = *(const float4*)src;
  float4 v1 = *(const float4*)(src + 4);
  bf16x8 o = { (bf16)v0.x, (bf16)v0.y, (bf16)v0.z, (bf16)v0.w,
               (bf16)v1.x, (bf16)v1.y, (bf16)v1.z, (bf16)v1.w };
  *(bf16x8*)(Vb2 + (size_t)id * 8) = o;
}

// ---------------- Gt2 = (W_gate @ W_enc)^T tiled [d/4][e][4]  (fp64 partials, atomic) ----------------
// R10: [d/4][e][4] tiling -> gating's per-lane 4 G values are ONE float4,
// wave-wide a contiguous 1KB stream.
__global__ void k_gmat(const float* __restrict__ Wg, const float* __restrict__ We,
                       float* __restrict__ Gt2) {
  int d = blockIdx.x * 256 + threadIdx.x;
  int e = blockIdx.y;
  int j0 = blockIdx.z * 128;
  double a0 = 0.0, a1 = 0.0, a2 = 0.0, a3 = 0.0;
  for (int j = j0; j < j0 + 128; j += 4) {
    a0 += (double)Wg[e * D_DIM + j + 0] * (double)We[(size_t)(j + 0) * D_DIM + d];
    a1 += (double)Wg[e * D_DIM + j + 1] * (double)We[(size_t)(j + 1) * D_DIM + d];
    a2 += (double)Wg[e * D_DIM + j + 2] * (double)We[(size_t)(j + 2) * D_DIM + d];
    a3 += (double)Wg[e * D_DIM + j + 3] * (double)We[(size_t)(j + 3) * D_DIM + d];
  }
  atomicAdd(&Gt2[(d >> 2) * 64 + e * 4 + (d & 3)], (float)((a0 + a1) + (a2 + a3)));
}

// ---------------- bgate[e] = W_gate[e,:] . b_enc ----------------
__global__ void k_bgate(const float* __restrict__ Wg, const float* __restrict__ be,
                        float* __restrict__ bg) {
  __shared__ double red[256];
  int e = blockIdx.x, t = threadIdx.x;
  double a = 0.0;
  for (int j = t; j < D_DIM; j += 256) a += (double)Wg[e * D_DIM + j] * (double)be[j];
  red[t] = a; __syncthreads();
  for (int s = 128; s > 0; s >>= 1) { if (t < s) red[t] += red[t + s]; __syncthreads(); }
  if (t == 0) bg[e] = (float)red[0];
}

// ---------------- fused gating + x->bf16 cast (R10: LDS-staged x, float4 Gt2) ----------------
// R9 post-mortem: latency-bound (2 HBM x loads + 4 scalar L2 G loads per iter,
// 1-deep prefetch, ~KBs in flight vs ~9KB/CU needed). R10: each wave stages
// its 2 token rows (8KB) via 8 fire-and-forget global_load_lds (one vmcnt
// drain), computes from LDS (broadcast reads), Gt2 gives 1 float4/iter
// (contiguous 1KB/wave L2 stream). Tail cast reads LDS, not global.
// Per-lane FMA order identical to R9.
__global__ __launch_bounds__(256) void k_gatecast(const float* __restrict__ x,
                                                  const float* __restrict__ Gt2,
                                                  const float* __restrict__ bg,
                                                  const float* __restrict__ gamma,
                                                  bf16* __restrict__ xb,
                                                  int* __restrict__ pk,
                                                  float2* __restrict__ wpair) {
  __shared__ float bufx[8][1024];   // 32KB: 8 token rows
  __shared__ float Ls[4 * 2 * NE];
  int tid = threadIdx.x;
  int wv = tid >> 6, lane = tid & 63;
  int g = lane & 15;
  int s = lane >> 4;
  int tokbase = blockIdx.x * 8 + wv * 2;

  // stage this wave's 2 rows: 8 x 1KB fire-and-forget
  const float* xr0 = x + (size_t)tokbase * D_DIM;
#pragma unroll
  for (int c = 0; c < 4; ++c) {
    gload16(xr0 + c * 256 + lane * 4, &bufx[wv * 2][c * 256 + lane * 4]);
    gload16(xr0 + D_DIM + c * 256 + lane * 4, &bufx[wv * 2 + 1][c * 256 + lane * 4]);
  }
  // first LDS read below forces the vmcnt drain (compiler-inserted)

  const float* Gq = Gt2 + s * 64 + g * 4;     // +256 floats per iter
  const float* b0p = &bufx[wv * 2][s * 4];
  const float* b1p = &bufx[wv * 2 + 1][s * 4];
  float acc0 = 0.0f, acc1 = 0.0f;
  float4 gv = *(const float4*)Gq;
  for (int it = 0; it < 64; ++it) {
    int nx = (it < 63) ? it + 1 : 0;          // last-iter prefetch clamped
    float4 gn = *(const float4*)(Gq + (size_t)nx * 256);
    float4 x0 = *(const float4*)(b0p + it * 16);
    float4 x1 = *(const float4*)(b1p + it * 16);
    acc0 += x0.x * gv.x + x0.y * gv.y + x0.z * gv.z + x0.w * gv.w;
    acc1 += x1.x * gv.x + x1.y * gv.y + x1.z * gv.z + x1.w * gv.w;
    gv = gn;
  }
  acc0 += __shfl_xor(acc0, 16); acc0 += __shfl_xor(acc0, 32);
  acc1 += __shfl_xor(acc1, 16); acc1 += __shfl_xor(acc1, 32);
  if (s == 0) {
    Ls[wv * 32 + g] = acc0;
    Ls[wv * 32 + 16 + g] = acc1;
  }

  // tail cast from LDS (no global re-read), coalesced bf16x4 stores
#pragma unroll
  for (int t = 0; t < 2; ++t) {
    const float4* src = (const float4*)&bufx[wv * 2 + t][0];
    bf16x4* dst = (bf16x4*)(xb + (size_t)(tokbase + t) * D_DIM);
#pragma unroll
    for (int r = 0; r < 4; ++r) {
      float4 v = src[lane + 64 * r];
      bf16x4 o = { (bf16)v.x, (bf16)v.y, (bf16)v.z, (bf16)v.w };
      dst[lane + 64 * r] = o;
    }
  }
  __syncthreads();

  if (lane < 2) {
    int t = lane;
    int tok = tokbase + t;
    const float* lrow = &Ls[wv * 32 + t * 16];
    float v1 = -1e30f, v2 = -1e30f; int i1 = 0, i2 = 0;
#pragma unroll
    for (int e = 0; e < NE; ++e) {
      float v = lrow[e] + bg[e];
      if (v > v1) { v2 = v1; i2 = i1; v1 = v; i1 = e; }
      else if (v > v2) { v2 = v; i2 = e; }
    }
    float e1 = expf(v2 - v1);
    float den = 1.0f + e1 + 1e-12f;
    float w0 = (1.0f / den) * gamma[i1];
    float w1 = (e1 / den) * gamma[i2];
    pk[tok] = i1 | (i2 << 8);
    wpair[tok] = make_float2(w0, w1);
  }
}

// ---------------- scatter: block-aggregated counting sort into per-bin lists ----------------
__global__ __launch_bounds__(256) void k_scatter(const int* __restrict__ pk,
                                                 const float2* __restrict__ wpair,
                                                 int* __restrict__ cnt,
                                                 int* __restrict__ lists,
                                                 float* __restrict__ wl) {
  __shared__ int lc[32];
  __shared__ int base[32];
  __shared__ int lc2[32];
  int tid = threadIdx.x;
  int tok = blockIdx.x * 256 + tid;
  if (tid < 32) { lc[tid] = 0; lc2[tid] = 0; }
  __syncthreads();
  int p = pk[tok];
  float2 w = wpair[tok];
  int b0 = p & 0xff;
  int b1 = 16 + ((p >> 8) & 0xff);
  atomicAdd(&lc[b0], 1);
  atomicAdd(&lc[b1], 1);
  __syncthreads();
  if (tid < 32 && lc[tid] > 0) base[tid] = atomicAdd(&cnt[tid], lc[tid]);
  __syncthreads();
  int r0 = base[b0] + atomicAdd(&lc2[b0], 1);
  lists[(size_t)b0 * NTOK + r0] = tok;
  wl[(size_t)b0 * NTOK + r0] = w.x;
  int r1 = base[b1] + atomicAdd(&lc2[b1], 1);
  lists[(size_t)b1 * NTOK + r1] = tok;
  wl[(size_t)b1 * NTOK + r1] = w.y;
}

// ---------------- block table: compact (bin, t0) list, one wave ----------------
__global__ void k_btab(const int* __restrict__ cnt, int2* __restrict__ btab,
                       int* __restrict__ nblk) {
  int lane = threadIdx.x;
  int nb = (lane < 32) ? ((cnt[lane] + 63) >> 6) : 0;
  int pfx = nb;
  for (int off = 1; off < 32; off <<= 1) {
    int v = __shfl_up(pfx, off);
    if (lane >= off) pfx += v;
  }
  int start = pfx - nb;
  if (lane < 32) {
    int c = cnt[lane];
    int i = 0;
    for (int t0 = 0; t0 < c; t0 += 64, ++i)
      btab[start + i] = make_int2(lane, t0);
  }
  if (lane == 31) *nblk = pfx;
}

// ---------------- encoder GEMM: out = x @ W_enc^T + b (fp32) ; encb = bf16(out) ----------------
__global__ __launch_bounds__(256) void k_encgemm(const bf16* __restrict__ A,
                                                 const bf16* __restrict__ W,
                                                 const float* __restrict__ bias,
                                                 float* __restrict__ out,
                                                 bf16* __restrict__ encb) {
  __shared__ bf16 As[128 * 64];
  __shared__ bf16 Bs[128 * 64];
  const int K = D_DIM;
  int tid = threadIdx.x;
  int bn = blockIdx.x * 128;
  int bm = blockIdx.y * 128;
  int lane = tid & 63, wv = tid >> 6;
  int wm = (wv >> 1) * 64, wn = (wv & 1) * 64;
  int srow = tid >> 3, scol = (tid & 7) * 8;
  int fr = lane & 15, fk = (lane >> 4) * 8;
  f32x4 acc[4][4] = {};
  for (int k0 = 0; k0 < K; k0 += 64) {
    __syncthreads();
#pragma unroll
    for (int p = 0; p < 4; ++p) {
      int r = p * 32 + srow;
      gload16(A + (size_t)(bm + r) * K + k0 + scol, &As[r * 64 + scol]);
    }
#pragma unroll
    for (int p = 0; p < 4; ++p) {
      int r = p * 32 + srow;
      gload16(W + (size_t)(bn + r) * K + k0 + scol, &Bs[r * 64 + scol]);
    }
    __syncthreads();
#pragma unroll
    for (int kk = 0; kk < 2; ++kk) {
      bf16x8 af[4], bv[4];
#pragma unroll
      for (int m = 0; m < 4; ++m)
        af[m] = *(const bf16x8*)&As[(wm + m * 16 + fr) * 64 + kk * 32 + fk];
#pragma unroll
      for (int n = 0; n < 4; ++n)
        bv[n] = *(const bf16x8*)&Bs[(wn + n * 16 + fr) * 64 + kk * 32 + fk];
#pragma unroll
      for (int m = 0; m < 4; ++m)
#pragma unroll
        for (int n = 0; n < 4; ++n)
          acc[m][n] = __builtin_amdgcn_mfma_f32_16x16x32_bf16(af[m], bv[n], acc[m][n], 0, 0, 0);
    }
  }
  int rg = (lane >> 4) * 4;
#pragma unroll
  for (int n = 0; n < 4; ++n) {
    int col = bn + wn + n * 16 + fr;
    float bval = bias[col];
#pragma unroll
    for (int m = 0; m < 4; ++m) {
#pragma unroll
      for (int r = 0; r < 4; ++r) {
        int row = bm + wm + m * 16 + rg + r;
        float v = acc[m][n][r] + bval;
        out[(size_t)row * D_DIM + col] = v;
        encb[(size_t)row * D_DIM + col] = (bf16)v;
      }
    }
  }
}

// ---------------- expert kernel (merged slots): S=silu(enc U^T)*coef -> delta = S V^T ----------------
__global__ __launch_bounds__(256) void k_expert(const bf16* __restrict__ encb,
                                                const bf16* __restrict__ Ub,
                                                const bf16* __restrict__ Vb2,
                                                const int* __restrict__ cnt,
                                                const int* __restrict__ lists,
                                                const float* __restrict__ wl,
                                                const int2* __restrict__ btab,
                                                const int* __restrict__ nblk,
                                                bf16* __restrict__ d0,
                                                bf16* __restrict__ d1) {
  int bid = blockIdx.x;
  if (bid >= *nblk) return;
  int2 bt = btab[bid];
  int bin = bt.x, t0 = bt.y;
  int slot = bin >> 4, e = bin & 15;
  int c = cnt[bin];
  int nrows = c - t0; if (nrows > 64) nrows = 64;
  const int* tl = lists + (size_t)bin * NTOK + t0;
  const float* wlp = wl + (size_t)bin * NTOK + t0;

  __shared__ int toks[64];
  __shared__ float coefs[64];
  __shared__ bf16 As[64 * 64];
  __shared__ bf16 Us[64 * 64];
  __shared__ bf16 Ss[64 * 64];

  int tid = threadIdx.x;
  if (tid < 64) {
    int rr = tid < nrows ? tid : nrows - 1;
    toks[tid] = tl[rr];
    coefs[tid] = tid < nrows ? wlp[tid] : 0.0f;
  }
  __syncthreads();

  int lane = tid & 63, wv = tid >> 6;
  int srow = tid >> 3, scol = (tid & 7) * 8;
  int fr = lane & 15, fk = (lane >> 4) * 8;
  size_t tokA0 = (size_t)toks[srow] * D_DIM;
  size_t tokA1 = (size_t)toks[32 + srow] * D_DIM;
  const bf16* Ue = Ub + (size_t)e * RK * D_DIM;
  f32x4 acc1[4] = {};

  for (int k0 = 0; k0 < D_DIM; k0 += 64) {
    __syncthreads();
    gload16(encb + tokA0 + k0 + scol, &As[srow * 64 + scol]);
    gload16(encb + tokA1 + k0 + scol, &As[(32 + srow) * 64 + scol]);
    gload16(Ue + (size_t)srow * D_DIM + k0 + scol, &Us[srow * 64 + scol]);
    gload16(Ue + (size_t)(32 + srow) * D_DIM + k0 + scol, &Us[(32 + srow) * 64 + scol]);
    __syncthreads();
#pragma unroll
    for (int kk = 0; kk < 2; ++kk) {
      bf16x8 af = *(const bf16x8*)&As[(wv * 16 + fr) * 64 + kk * 32 + fk];
#pragma unroll
      for (int n = 0; n < 4; ++n) {
        bf16x8 bv = *(const bf16x8*)&Us[(n * 16 + fr) * 64 + kk * 32 + fk];
        acc1[n] = __builtin_amdgcn_mfma_f32_16x16x32_bf16(af, bv, acc1[n], 0, 0, 0);
      }
    }
  }
  int rg = (lane >> 4) * 4;
#pragma unroll
  for (int n = 0; n < 4; ++n)
#pragma unroll
    for (int r = 0; r < 4; ++r) {
      int row = wv * 16 + rg + r;
      float v = acc1[n][r];
      float s = v / (1.0f + __expf(-v));
      Ss[row * 64 + n * 16 + fr] = (bf16)(s * coefs[row]);
    }
  __syncthreads();
  bf16x8 a2[4][2];
#pragma unroll
  for (int m = 0; m < 4; ++m)
#pragma unroll
    for (int kk = 0; kk < 2; ++kk)
      a2[m][kk] = *(const bf16x8*)&Ss[(m * 16 + fr) * 64 + kk * 32 + fk];

  const bf16* Ve2 = Vb2 + (size_t)e * RK * D_DIM;
  bf16* dst = slot ? d1 : d0;
  int rb0 = lane >> 4;
  int colbase = wv * 256;
  for (int nj = 0; nj < 16; ++nj) {
    int dcol = colbase + nj * 16 + fr;
    bf16x8 b0 = *(const bf16x8*)&Ve2[((size_t)rb0 * D_DIM + dcol) * 8];
    bf16x8 b1 = *(const bf16x8*)&Ve2[((size_t)(rb0 + 4) * D_DIM + dcol) * 8];
#pragma unroll
    for (int m = 0; m < 4; ++m) {
      f32x4 a = {};
      a = __builtin_amdgcn_mfma_f32_16x16x32_bf16(a2[m][0], b0, a, 0, 0, 0);
      a = __builtin_amdgcn_mfma_f32_16x16x32_bf16(a2[m][1], b1, a, 0, 0, 0);
#pragma unroll
      for (int r = 0; r < 4; ++r) {
        int row = m * 16 + rg + r;
        if (row < nrows) {
          dst[(size_t)toks[row] * D_DIM + dcol] = (bf16)a[r];
        }
      }
    }
  }
}

// ---------------- final: out = enc(in out) + d0 + d1 ----------------
__global__ __launch_bounds__(256) void k_final(float* __restrict__ out,
                                               const bf16* __restrict__ d0,
                                               const bf16* __restrict__ d1) {
  size_t i = ((size_t)blockIdx.x * 256 + threadIdx.x) * 8;
  float4 o0 = *(float4*)(out + i);
  float4 o1 = *(float4*)(out + i + 4);
  bf16x8 a = *(const bf16x8*)(d0 + i);
  bf16x8 b = *(const bf16x8*)(d1 + i);
  o0.x += (float)a[0] + (float)b[0];
  o0.y += (float)a[1] + (float)b[1];
  o0.z += (float)a[2] + (float)b[2];
  o0.w += (float)a[3] + (float)b[3];
  o1.x += (float)a[4] + (float)b[4];
  o1.y += (float)a[5] + (float)b[5];
  o1.z += (float)a[6] + (float)b[6];
  o1.w += (float)a[7] + (float)b[7];
  *(float4*)(out + i) = o0;
  *(float4*)(out + i + 4) = o1;
}

extern "C" void kernel_launch(void* const* d_in, const int* in_sizes, int n_in,
                              void* d_out, int out_size, void* d_ws, size_t ws_size,
                              hipStream_t stream) {
  const float* x   = (const float*)d_in[0];
  const float* We  = (const float*)d_in[1];
  const float* be  = (const float*)d_in[2];
  const float* Wg  = (const float*)d_in[3];
  const float* U   = (const float*)d_in[4];
  const float* V   = (const float*)d_in[5];
  const float* gam = (const float*)d_in[6];
  float* out = (float*)d_out;
  char* ws = (char*)d_ws;

  int*    cnt  = (int*)(ws + 0);                       // 128 B   (zeroed)
  float*  Gt2  = (float*)(ws + 256);                   // 64 KiB  (zeroed), [d/4][e][4]
  float*  bg   = (float*)(ws + 66048);                 // 64 B
  int2*   btab = (int2*)(ws + 66176);                  // 4.25 KiB
  int*    nblk = (int*)(ws + 70656);                   // 4 B
  bf16*   xb   = (bf16*)(ws + 131072);                 // 32 MiB (aliased: d0 after encgemm)
  bf16*   d0   = (bf16*)(ws + 131072);
  bf16*   encb = (bf16*)(ws + 131072 + 33554432);      // 32 MiB
  char*   base = ws + 131072 + 2 * 33554432;
  bf16*   Wb   = (bf16*)(base);                        // 2 MiB
  bf16*   Ubf  = (bf16*)(base + 2097152);              // 2 MiB
  bf16*   Vb2  = (bf16*)(base + 2 * 2097152);          // 2 MiB  [e][r/8][d][8]
  int*    lists= (int*)(base + 3 * 2097152);           // 2 MiB
  float*  wl   = (float*)(base + 4 * 2097152);         // 2 MiB
  int*    pk   = (int*)(base + 5 * 2097152);           // 64 KiB
  float2* wpr  = (float2*)(base + 5 * 2097152 + 131072); // 128 KiB
  bf16*   d1   = (bf16*)(base + 5 * 2097152 + 131072 + 131072 + 131072); // 32 MiB

  hipMemsetAsync(ws, 0, 66048, stream);

  k_cast<<<1024, 256, 0, stream>>>(We, Wb, 1048576 / 4);
  k_cast<<<1024, 256, 0, stream>>>(U, Ubf, 1048576 / 4);
  k_castv<<<512, 256, 0, stream>>>(V, Vb2);

  dim3 gg(4, 16, 8);
  k_gmat<<<gg, 256, 0, stream>>>(Wg, We, Gt2);
  k_bgate<<<16, 256, 0, stream>>>(Wg, be, bg);

  k_gatecast<<<2048, 256, 0, stream>>>(x, Gt2, bg, gam, xb, pk, wpr);
  k_scatter<<<64, 256, 0, stream>>>(pk, wpr, cnt, lists, wl);
  k_btab<<<1, 64, 0, stream>>>(cnt, btab, nblk);

  dim3 ge(8, 128);
  k_encgemm<<<ge, 256, 0, stream>>>(xb, Wb, be, out, encb);

  k_expert<<<544, 256, 0, stream>>>(encb, Ubf, Vb2, cnt, lists, wl, btab, nblk, d0, d1);
  k_final<<<8192, 256, 0, stream>>>(out, d0, d1);
}

// Round 11
// 189.908 us; speedup vs baseline: 2.9297x; 1.0878x over previous
//
#include <hip/hip_runtime.h>
#include <hip/hip_bf16.h>

#define D_DIM 1024
#define NE 16
#define RK 64
#define NTOK 16384

typedef __bf16 bf16;
typedef __bf16 bf16x8 __attribute__((ext_vector_type(8)));
typedef __bf16 bf16x4 __attribute__((ext_vector_type(4)));
typedef float f32x4 __attribute__((ext_vector_type(4)));

__device__ __forceinline__ void gload16(const void* g, void* l) {
  __builtin_amdgcn_global_load_lds((const __attribute__((address_space(1))) unsigned int*)g,
                                   (__attribute__((address_space(3))) unsigned int*)l,
                                   16, 0, 0);
}

// ---------------- casts (weights only) ----------------
__global__ void k_cast(const float* __restrict__ s, bf16* __restrict__ d, int n4) {
  int i = blockIdx.x * blockDim.x + threadIdx.x;
  if (i >= n4) return;
  float4 v = ((const float4*)s)[i];
  bf16x4 o = { (bf16)v.x, (bf16)v.y, (bf16)v.z, (bf16)v.w };
  ((bf16x4*)d)[i] = o;
}

// ---------------- V cast + relayout: V[e][d][r] -> Vb2[e][r/8][d][r%8] ----------------
__global__ void k_castv(const float* __restrict__ V, bf16* __restrict__ Vb2) {
  int id = blockIdx.x * 256 + threadIdx.x;
  int d = id & 1023;
  int rb = (id >> 10) & 7;
  int e = id >> 13;
  const float* src = V + ((size_t)(e * 1024 + d)) * 64 + rb * 8;
  float4 v0 = *(const float4*)src;
  float4 v1 = *(const float4*)(src + 4);
  bf16x8 o = { (bf16)v0.x, (bf16)v0.y, (bf16)v0.z, (bf16)v0.w,
               (bf16)v1.x, (bf16)v1.y, (bf16)v1.z, (bf16)v1.w };
  *(bf16x8*)(Vb2 + (size_t)id * 8) = o;
}

// ---------------- Gt2 = (W_gate @ W_enc)^T tiled [d/4][e][4]  (fp64 partials, atomic) ----------------
__global__ void k_gmat(const float* __restrict__ Wg, const float* __restrict__ We,
                       float* __restrict__ Gt2) {
  int d = blockIdx.x * 256 + threadIdx.x;
  int e = blockIdx.y;
  int j0 = blockIdx.z * 128;
  double a0 = 0.0, a1 = 0.0, a2 = 0.0, a3 = 0.0;
  for (int j = j0; j < j0 + 128; j += 4) {
    a0 += (double)Wg[e * D_DIM + j + 0] * (double)We[(size_t)(j + 0) * D_DIM + d];
    a1 += (double)Wg[e * D_DIM + j + 1] * (double)We[(size_t)(j + 1) * D_DIM + d];
    a2 += (double)Wg[e * D_DIM + j + 2] * (double)We[(size_t)(j + 2) * D_DIM + d];
    a3 += (double)Wg[e * D_DIM + j + 3] * (double)We[(size_t)(j + 3) * D_DIM + d];
  }
  atomicAdd(&Gt2[(d >> 2) * 64 + e * 4 + (d & 3)], (float)((a0 + a1) + (a2 + a3)));
}

// ---------------- bgate[e] = W_gate[e,:] . b_enc ----------------
__global__ void k_bgate(const float* __restrict__ Wg, const float* __restrict__ be,
                        float* __restrict__ bg) {
  __shared__ double red[256];
  int e = blockIdx.x, t = threadIdx.x;
  double a = 0.0;
  for (int j = t; j < D_DIM; j += 256) a += (double)Wg[e * D_DIM + j] * (double)be[j];
  red[t] = a; __syncthreads();
  for (int s = 128; s > 0; s >>= 1) { if (t < s) red[t] += red[t + s]; __syncthreads(); }
  if (t == 0) bg[e] = (float)red[0];
}

// ---------------- fused gating + x->bf16 cast (LDS-staged x, float4 Gt2) ----------------
__global__ __launch_bounds__(256) void k_gatecast(const float* __restrict__ x,
                                                  const float* __restrict__ Gt2,
                                                  const float* __restrict__ bg,
                                                  const float* __restrict__ gamma,
                                                  bf16* __restrict__ xb,
                                                  int* __restrict__ pk,
                                                  float2* __restrict__ wpair) {
  __shared__ float bufx[8][1024];
  __shared__ float Ls[4 * 2 * NE];
  int tid = threadIdx.x;
  int wv = tid >> 6, lane = tid & 63;
  int g = lane & 15;
  int s = lane >> 4;
  int tokbase = blockIdx.x * 8 + wv * 2;

  const float* xr0 = x + (size_t)tokbase * D_DIM;
#pragma unroll
  for (int c = 0; c < 4; ++c) {
    gload16(xr0 + c * 256 + lane * 4, &bufx[wv * 2][c * 256 + lane * 4]);
    gload16(xr0 + D_DIM + c * 256 + lane * 4, &bufx[wv * 2 + 1][c * 256 + lane * 4]);
  }

  const float* Gq = Gt2 + s * 64 + g * 4;
  const float* b0p = &bufx[wv * 2][s * 4];
  const float* b1p = &bufx[wv * 2 + 1][s * 4];
  float acc0 = 0.0f, acc1 = 0.0f;
  float4 gv = *(const float4*)Gq;
  for (int it = 0; it < 64; ++it) {
    int nx = (it < 63) ? it + 1 : 0;
    float4 gn = *(const float4*)(Gq + (size_t)nx * 256);
    float4 x0 = *(const float4*)(b0p + it * 16);
    float4 x1 = *(const float4*)(b1p + it * 16);
    acc0 += x0.x * gv.x + x0.y * gv.y + x0.z * gv.z + x0.w * gv.w;
    acc1 += x1.x * gv.x + x1.y * gv.y + x1.z * gv.z + x1.w * gv.w;
    gv = gn;
  }
  acc0 += __shfl_xor(acc0, 16); acc0 += __shfl_xor(acc0, 32);
  acc1 += __shfl_xor(acc1, 16); acc1 += __shfl_xor(acc1, 32);
  if (s == 0) {
    Ls[wv * 32 + g] = acc0;
    Ls[wv * 32 + 16 + g] = acc1;
  }

#pragma unroll
  for (int t = 0; t < 2; ++t) {
    const float4* src = (const float4*)&bufx[wv * 2 + t][0];
    bf16x4* dst = (bf16x4*)(xb + (size_t)(tokbase + t) * D_DIM);
#pragma unroll
    for (int r = 0; r < 4; ++r) {
      float4 v = src[lane + 64 * r];
      bf16x4 o = { (bf16)v.x, (bf16)v.y, (bf16)v.z, (bf16)v.w };
      dst[lane + 64 * r] = o;
    }
  }
  __syncthreads();

  if (lane < 2) {
    int t = lane;
    int tok = tokbase + t;
    const float* lrow = &Ls[wv * 32 + t * 16];
    float v1 = -1e30f, v2 = -1e30f; int i1 = 0, i2 = 0;
#pragma unroll
    for (int e = 0; e < NE; ++e) {
      float v = lrow[e] + bg[e];
      if (v > v1) { v2 = v1; i2 = i1; v1 = v; i1 = e; }
      else if (v > v2) { v2 = v; i2 = e; }
    }
    float e1 = expf(v2 - v1);
    float den = 1.0f + e1 + 1e-12f;
    float w0 = (1.0f / den) * gamma[i1];
    float w1 = (e1 / den) * gamma[i2];
    pk[tok] = i1 | (i2 << 8);
    wpair[tok] = make_float2(w0, w1);
  }
}

// ---------------- scatter: block-aggregated counting sort into per-bin lists ----------------
__global__ __launch_bounds__(256) void k_scatter(const int* __restrict__ pk,
                                                 const float2* __restrict__ wpair,
                                                 int* __restrict__ cnt,
                                                 int* __restrict__ lists,
                                                 float* __restrict__ wl) {
  __shared__ int lc[32];
  __shared__ int base[32];
  __shared__ int lc2[32];
  int tid = threadIdx.x;
  int tok = blockIdx.x * 256 + tid;
  if (tid < 32) { lc[tid] = 0; lc2[tid] = 0; }
  __syncthreads();
  int p = pk[tok];
  float2 w = wpair[tok];
  int b0 = p & 0xff;
  int b1 = 16 + ((p >> 8) & 0xff);
  atomicAdd(&lc[b0], 1);
  atomicAdd(&lc[b1], 1);
  __syncthreads();
  if (tid < 32 && lc[tid] > 0) base[tid] = atomicAdd(&cnt[tid], lc[tid]);
  __syncthreads();
  int r0 = base[b0] + atomicAdd(&lc2[b0], 1);
  lists[(size_t)b0 * NTOK + r0] = tok;
  wl[(size_t)b0 * NTOK + r0] = w.x;
  int r1 = base[b1] + atomicAdd(&lc2[b1], 1);
  lists[(size_t)b1 * NTOK + r1] = tok;
  wl[(size_t)b1 * NTOK + r1] = w.y;
}

// ---------------- block table: compact (bin, t0) list, one wave ----------------
__global__ void k_btab(const int* __restrict__ cnt, int2* __restrict__ btab,
                       int* __restrict__ nblk) {
  int lane = threadIdx.x;
  int nb = (lane < 32) ? ((cnt[lane] + 63) >> 6) : 0;
  int pfx = nb;
  for (int off = 1; off < 32; off <<= 1) {
    int v = __shfl_up(pfx, off);
    if (lane >= off) pfx += v;
  }
  int start = pfx - nb;
  if (lane < 32) {
    int c = cnt[lane];
    int i = 0;
    for (int t0 = 0; t0 < c; t0 += 64, ++i)
      btab[start + i] = make_int2(lane, t0);
  }
  if (lane == 31) *nblk = pfx;
}

// ---------------- encoder GEMM: encb = bf16(x @ W_enc^T + b) ----------------
// R11: (1) XCD-strip swizzle — 1D grid, XCD c (= blockIdx%8) owns bm strip
// [16c,16c+16): its A working set = 4MB = one XCD L2; all 8 bn tiles reuse
// it from L2 instead of 8 XCDs each fetching from HBM/L3 (FETCH 133MB->~40).
// (2) fp32 `out` write dropped (-64MB); k_final composes from encb
// (adds ~0.03 bf16-rounding of encoded; 0.031 -> ~0.06 < 0.13 threshold).
__global__ __launch_bounds__(256) void k_encgemm(const bf16* __restrict__ A,
                                                 const bf16* __restrict__ W,
                                                 const float* __restrict__ bias,
                                                 bf16* __restrict__ encb) {
  __shared__ bf16 As[128 * 64];
  __shared__ bf16 Bs[128 * 64];
  const int K = D_DIM;
  int tid = threadIdx.x;
  int w = blockIdx.x;          // 1024 blocks; HW round-robins w%8 across XCDs
  int xcd = w & 7;
  int i = w >> 3;              // [0,128)
  int bm = (xcd * 16 + (i & 15)) * 128;
  int bn = (i >> 4) * 128;
  int lane = tid & 63, wv = tid >> 6;
  int wm = (wv >> 1) * 64, wn = (wv & 1) * 64;
  int srow = tid >> 3, scol = (tid & 7) * 8;
  int fr = lane & 15, fk = (lane >> 4) * 8;
  f32x4 acc[4][4] = {};
  for (int k0 = 0; k0 < K; k0 += 64) {
    __syncthreads();
#pragma unroll
    for (int p = 0; p < 4; ++p) {
      int r = p * 32 + srow;
      gload16(A + (size_t)(bm + r) * K + k0 + scol, &As[r * 64 + scol]);
    }
#pragma unroll
    for (int p = 0; p < 4; ++p) {
      int r = p * 32 + srow;
      gload16(W + (size_t)(bn + r) * K + k0 + scol, &Bs[r * 64 + scol]);
    }
    __syncthreads();
#pragma unroll
    for (int kk = 0; kk < 2; ++kk) {
      bf16x8 af[4], bv[4];
#pragma unroll
      for (int m = 0; m < 4; ++m)
        af[m] = *(const bf16x8*)&As[(wm + m * 16 + fr) * 64 + kk * 32 + fk];
#pragma unroll
      for (int n = 0; n < 4; ++n)
        bv[n] = *(const bf16x8*)&Bs[(wn + n * 16 + fr) * 64 + kk * 32 + fk];
#pragma unroll
      for (int m = 0; m < 4; ++m)
#pragma unroll
        for (int n = 0; n < 4; ++n)
          acc[m][n] = __builtin_amdgcn_mfma_f32_16x16x32_bf16(af[m], bv[n], acc[m][n], 0, 0, 0);
    }
  }
  int rg = (lane >> 4) * 4;
#pragma unroll
  for (int n = 0; n < 4; ++n) {
    int col = bn + wn + n * 16 + fr;
    float bval = bias[col];
#pragma unroll
    for (int m = 0; m < 4; ++m) {
#pragma unroll
      for (int r = 0; r < 4; ++r) {
        int row = bm + wm + m * 16 + rg + r;
        encb[(size_t)row * D_DIM + col] = (bf16)(acc[m][n][r] + bval);
      }
    }
  }
}

// ---------------- expert kernel (merged slots): S=silu(enc U^T)*coef -> delta = S V^T ----------------
__global__ __launch_bounds__(256) void k_expert(const bf16* __restrict__ encb,
                                                const bf16* __restrict__ Ub,
                                                const bf16* __restrict__ Vb2,
                                                const int* __restrict__ cnt,
                                                const int* __restrict__ lists,
                                                const float* __restrict__ wl,
                                                const int2* __restrict__ btab,
                                                const int* __restrict__ nblk,
                                                bf16* __restrict__ d0,
                                                bf16* __restrict__ d1) {
  int bid = blockIdx.x;
  if (bid >= *nblk) return;
  int2 bt = btab[bid];
  int bin = bt.x, t0 = bt.y;
  int slot = bin >> 4, e = bin & 15;
  int c = cnt[bin];
  int nrows = c - t0; if (nrows > 64) nrows = 64;
  const int* tl = lists + (size_t)bin * NTOK + t0;
  const float* wlp = wl + (size_t)bin * NTOK + t0;

  __shared__ int toks[64];
  __shared__ float coefs[64];
  __shared__ bf16 As[64 * 64];
  __shared__ bf16 Us[64 * 64];
  __shared__ bf16 Ss[64 * 64];

  int tid = threadIdx.x;
  if (tid < 64) {
    int rr = tid < nrows ? tid : nrows - 1;
    toks[tid] = tl[rr];
    coefs[tid] = tid < nrows ? wlp[tid] : 0.0f;
  }
  __syncthreads();

  int lane = tid & 63, wv = tid >> 6;
  int srow = tid >> 3, scol = (tid & 7) * 8;
  int fr = lane & 15, fk = (lane >> 4) * 8;
  size_t tokA0 = (size_t)toks[srow] * D_DIM;
  size_t tokA1 = (size_t)toks[32 + srow] * D_DIM;
  const bf16* Ue = Ub + (size_t)e * RK * D_DIM;
  f32x4 acc1[4] = {};

  for (int k0 = 0; k0 < D_DIM; k0 += 64) {
    __syncthreads();
    gload16(encb + tokA0 + k0 + scol, &As[srow * 64 + scol]);
    gload16(encb + tokA1 + k0 + scol, &As[(32 + srow) * 64 + scol]);
    gload16(Ue + (size_t)srow * D_DIM + k0 + scol, &Us[srow * 64 + scol]);
    gload16(Ue + (size_t)(32 + srow) * D_DIM + k0 + scol, &Us[(32 + srow) * 64 + scol]);
    __syncthreads();
#pragma unroll
    for (int kk = 0; kk < 2; ++kk) {
      bf16x8 af = *(const bf16x8*)&As[(wv * 16 + fr) * 64 + kk * 32 + fk];
#pragma unroll
      for (int n = 0; n < 4; ++n) {
        bf16x8 bv = *(const bf16x8*)&Us[(n * 16 + fr) * 64 + kk * 32 + fk];
        acc1[n] = __builtin_amdgcn_mfma_f32_16x16x32_bf16(af, bv, acc1[n], 0, 0, 0);
      }
    }
  }
  int rg = (lane >> 4) * 4;
#pragma unroll
  for (int n = 0; n < 4; ++n)
#pragma unroll
    for (int r = 0; r < 4; ++r) {
      int row = wv * 16 + rg + r;
      float v = acc1[n][r];
      float s = v / (1.0f + __expf(-v));
      Ss[row * 64 + n * 16 + fr] = (bf16)(s * coefs[row]);
    }
  __syncthreads();
  bf16x8 a2[4][2];
#pragma unroll
  for (int m = 0; m < 4; ++m)
#pragma unroll
    for (int kk = 0; kk < 2; ++kk)
      a2[m][kk] = *(const bf16x8*)&Ss[(m * 16 + fr) * 64 + kk * 32 + fk];

  const bf16* Ve2 = Vb2 + (size_t)e * RK * D_DIM;
  bf16* dst = slot ? d1 : d0;
  int rb0 = lane >> 4;
  int colbase = wv * 256;
  for (int nj = 0; nj < 16; ++nj) {
    int dcol = colbase + nj * 16 + fr;
    bf16x8 b0 = *(const bf16x8*)&Ve2[((size_t)rb0 * D_DIM + dcol) * 8];
    bf16x8 b1 = *(const bf16x8*)&Ve2[((size_t)(rb0 + 4) * D_DIM + dcol) * 8];
#pragma unroll
    for (int m = 0; m < 4; ++m) {
      f32x4 a = {};
      a = __builtin_amdgcn_mfma_f32_16x16x32_bf16(a2[m][0], b0, a, 0, 0, 0);
      a = __builtin_amdgcn_mfma_f32_16x16x32_bf16(a2[m][1], b1, a, 0, 0, 0);
#pragma unroll
      for (int r = 0; r < 4; ++r) {
        int row = m * 16 + rg + r;
        if (row < nrows) {
          dst[(size_t)toks[row] * D_DIM + dcol] = (bf16)a[r];
        }
      }
    }
  }
}

// ---------------- final: out = encb + d0 + d1 (pure streams, no RMW) ----------------
__global__ __launch_bounds__(256) void k_final(float* __restrict__ out,
                                               const bf16* __restrict__ encb,
                                               const bf16* __restrict__ d0,
                                               const bf16* __restrict__ d1) {
  size_t i = ((size_t)blockIdx.x * 256 + threadIdx.x) * 8;
  bf16x8 e = *(const bf16x8*)(encb + i);
  bf16x8 a = *(const bf16x8*)(d0 + i);
  bf16x8 b = *(const bf16x8*)(d1 + i);
  float4 o0, o1;
  o0.x = (float)e[0] + (float)a[0] + (float)b[0];
  o0.y = (float)e[1] + (float)a[1] + (float)b[1];
  o0.z = (float)e[2] + (float)a[2] + (float)b[2];
  o0.w = (float)e[3] + (float)a[3] + (float)b[3];
  o1.x = (float)e[4] + (float)a[4] + (float)b[4];
  o1.y = (float)e[5] + (float)a[5] + (float)b[5];
  o1.z = (float)e[6] + (float)a[6] + (float)b[6];
  o1.w = (float)e[7] + (float)a[7] + (float)b[7];
  *(float4*)(out + i) = o0;
  *(float4*)(out + i + 4) = o1;
}

extern "C" void kernel_launch(void* const* d_in, const int* in_sizes, int n_in,
                              void* d_out, int out_size, void* d_ws, size_t ws_size,
                              hipStream_t stream) {
  const float* x   = (const float*)d_in[0];
  const float* We  = (const float*)d_in[1];
  const float* be  = (const float*)d_in[2];
  const float* Wg  = (const float*)d_in[3];
  const float* U   = (const float*)d_in[4];
  const float* V   = (const float*)d_in[5];
  const float* gam = (const float*)d_in[6];
  float* out = (float*)d_out;
  char* ws = (char*)d_ws;

  int*    cnt  = (int*)(ws + 0);                       // 128 B   (zeroed)
  float*  Gt2  = (float*)(ws + 256);                   // 64 KiB  (zeroed), [d/4][e][4]
  float*  bg   = (float*)(ws + 66048);                 // 64 B
  int2*   btab = (int2*)(ws + 66176);                  // 4.25 KiB
  int*    nblk = (int*)(ws + 70656);                   // 4 B
  bf16*   xb   = (bf16*)(ws + 131072);                 // 32 MiB (aliased: d0 after encgemm)
  bf16*   d0   = (bf16*)(ws + 131072);
  bf16*   encb = (bf16*)(ws + 131072 + 33554432);      // 32 MiB
  char*   base = ws + 131072 + 2 * 33554432;
  bf16*   Wb   = (bf16*)(base);                        // 2 MiB
  bf16*   Ubf  = (bf16*)(base + 2097152);              // 2 MiB
  bf16*   Vb2  = (bf16*)(base + 2 * 2097152);          // 2 MiB  [e][r/8][d][8]
  int*    lists= (int*)(base + 3 * 2097152);           // 2 MiB
  float*  wl   = (float*)(base + 4 * 2097152);         // 2 MiB
  int*    pk   = (int*)(base + 5 * 2097152);           // 64 KiB
  float2* wpr  = (float2*)(base + 5 * 2097152 + 131072); // 128 KiB
  bf16*   d1   = (bf16*)(base + 5 * 2097152 + 131072 + 131072 + 131072); // 32 MiB

  hipMemsetAsync(ws, 0, 66048, stream);

  k_cast<<<1024, 256, 0, stream>>>(We, Wb, 1048576 / 4);
  k_cast<<<1024, 256, 0, stream>>>(U, Ubf, 1048576 / 4);
  k_castv<<<512, 256, 0, stream>>>(V, Vb2);

  dim3 gg(4, 16, 8);
  k_gmat<<<gg, 256, 0, stream>>>(Wg, We, Gt2);
  k_bgate<<<16, 256, 0, stream>>>(Wg, be, bg);

  k_gatecast<<<2048, 256, 0, stream>>>(x, Gt2, bg, gam, xb, pk, wpr);
  k_scatter<<<64, 256, 0, stream>>>(pk, wpr, cnt, lists, wl);
  k_btab<<<1, 64, 0, stream>>>(cnt, btab, nblk);

  k_encgemm<<<1024, 256, 0, stream>>>(xb, Wb, be, encb);

  k_expert<<<544, 256, 0, stream>>>(encb, Ubf, Vb2, cnt, lists, wl, btab, nblk, d0, d1);
  k_final<<<8192, 256, 0, stream>>>(out, encb, d0, d1);
}

// Round 12
// 183.776 us; speedup vs baseline: 3.0274x; 1.0334x over previous
//
#include <hip/hip_runtime.h>
#include <hip/hip_bf16.h>

#define D_DIM 1024
#define NE 16
#define RK 64
#define NTOK 16384

typedef __bf16 bf16;
typedef __bf16 bf16x8 __attribute__((ext_vector_type(8)));
typedef __bf16 bf16x4 __attribute__((ext_vector_type(4)));
typedef float f32x4 __attribute__((ext_vector_type(4)));

__device__ __forceinline__ void gload16(const void* g, void* l) {
  __builtin_amdgcn_global_load_lds((const __attribute__((address_space(1))) unsigned int*)g,
                                   (__attribute__((address_space(3))) unsigned int*)l,
                                   16, 0, 0);
}

// ---------------- casts (weights only) ----------------
__global__ void k_cast(const float* __restrict__ s, bf16* __restrict__ d, int n4) {
  int i = blockIdx.x * blockDim.x + threadIdx.x;
  if (i >= n4) return;
  float4 v = ((const float4*)s)[i];
  bf16x4 o = { (bf16)v.x, (bf16)v.y, (bf16)v.z, (bf16)v.w };
  ((bf16x4*)d)[i] = o;
}

// ---------------- V cast + relayout: V[e][d][r] -> Vb2[e][r/8][d][r%8] ----------------
__global__ void k_castv(const float* __restrict__ V, bf16* __restrict__ Vb2) {
  int id = blockIdx.x * 256 + threadIdx.x;
  int d = id & 1023;
  int rb = (id >> 10) & 7;
  int e = id >> 13;
  const float* src = V + ((size_t)(e * 1024 + d)) * 64 + rb * 8;
  float4 v0 = *(const float4*)src;
  float4 v1 = *(const float4*)(src + 4);
  bf16x8 o = { (bf16)v0.x, (bf16)v0.y, (bf16)v0.z, (bf16)v0.w,
               (bf16)v1.x, (bf16)v1.y, (bf16)v1.z, (bf16)v1.w };
  *(bf16x8*)(Vb2 + (size_t)id * 8) = o;
}

// ---------------- Gt2 = (W_gate @ W_enc)^T tiled [d/4][e][4]  (fp64 partials, atomic) ----------------
__global__ void k_gmat(const float* __restrict__ Wg, const float* __restrict__ We,
                       float* __restrict__ Gt2) {
  int d = blockIdx.x * 256 + threadIdx.x;
  int e = blockIdx.y;
  int j0 = blockIdx.z * 128;
  double a0 = 0.0, a1 = 0.0, a2 = 0.0, a3 = 0.0;
  for (int j = j0; j < j0 + 128; j += 4) {
    a0 += (double)Wg[e * D_DIM + j + 0] * (double)We[(size_t)(j + 0) * D_DIM + d];
    a1 += (double)Wg[e * D_DIM + j + 1] * (double)We[(size_t)(j + 1) * D_DIM + d];
    a2 += (double)Wg[e * D_DIM + j + 2] * (double)We[(size_t)(j + 2) * D_DIM + d];
    a3 += (double)Wg[e * D_DIM + j + 3] * (double)We[(size_t)(j + 3) * D_DIM + d];
  }
  atomicAdd(&Gt2[(d >> 2) * 64 + e * 4 + (d & 3)], (float)((a0 + a1) + (a2 + a3)));
}

// ---------------- bgate[e] = W_gate[e,:] . b_enc ----------------
__global__ void k_bgate(const float* __restrict__ Wg, const float* __restrict__ be,
                        float* __restrict__ bg) {
  __shared__ double red[256];
  int e = blockIdx.x, t = threadIdx.x;
  double a = 0.0;
  for (int j = t; j < D_DIM; j += 256) a += (double)Wg[e * D_DIM + j] * (double)be[j];
  red[t] = a; __syncthreads();
  for (int s = 128; s > 0; s >>= 1) { if (t < s) red[t] += red[t + s]; __syncthreads(); }
  if (t == 0) bg[e] = (float)red[0];
}

// ---------------- fused gating + x->bf16 cast (LDS-staged x, float4 Gt2) ----------------
__global__ __launch_bounds__(256) void k_gatecast(const float* __restrict__ x,
                                                  const float* __restrict__ Gt2,
                                                  const float* __restrict__ bg,
                                                  const float* __restrict__ gamma,
                                                  bf16* __restrict__ xb,
                                                  int* __restrict__ pk,
                                                  float2* __restrict__ wpair) {
  __shared__ float bufx[8][1024];
  __shared__ float Ls[4 * 2 * NE];
  int tid = threadIdx.x;
  int wv = tid >> 6, lane = tid & 63;
  int g = lane & 15;
  int s = lane >> 4;
  int tokbase = blockIdx.x * 8 + wv * 2;

  const float* xr0 = x + (size_t)tokbase * D_DIM;
#pragma unroll
  for (int c = 0; c < 4; ++c) {
    gload16(xr0 + c * 256 + lane * 4, &bufx[wv * 2][c * 256 + lane * 4]);
    gload16(xr0 + D_DIM + c * 256 + lane * 4, &bufx[wv * 2 + 1][c * 256 + lane * 4]);
  }

  const float* Gq = Gt2 + s * 64 + g * 4;
  const float* b0p = &bufx[wv * 2][s * 4];
  const float* b1p = &bufx[wv * 2 + 1][s * 4];
  float acc0 = 0.0f, acc1 = 0.0f;
  float4 gv = *(const float4*)Gq;
  for (int it = 0; it < 64; ++it) {
    int nx = (it < 63) ? it + 1 : 0;
    float4 gn = *(const float4*)(Gq + (size_t)nx * 256);
    float4 x0 = *(const float4*)(b0p + it * 16);
    float4 x1 = *(const float4*)(b1p + it * 16);
    acc0 += x0.x * gv.x + x0.y * gv.y + x0.z * gv.z + x0.w * gv.w;
    acc1 += x1.x * gv.x + x1.y * gv.y + x1.z * gv.z + x1.w * gv.w;
    gv = gn;
  }
  acc0 += __shfl_xor(acc0, 16); acc0 += __shfl_xor(acc0, 32);
  acc1 += __shfl_xor(acc1, 16); acc1 += __shfl_xor(acc1, 32);
  if (s == 0) {
    Ls[wv * 32 + g] = acc0;
    Ls[wv * 32 + 16 + g] = acc1;
  }

#pragma unroll
  for (int t = 0; t < 2; ++t) {
    const float4* src = (const float4*)&bufx[wv * 2 + t][0];
    bf16x4* dst = (bf16x4*)(xb + (size_t)(tokbase + t) * D_DIM);
#pragma unroll
    for (int r = 0; r < 4; ++r) {
      float4 v = src[lane + 64 * r];
      bf16x4 o = { (bf16)v.x, (bf16)v.y, (bf16)v.z, (bf16)v.w };
      dst[lane + 64 * r] = o;
    }
  }
  __syncthreads();

  if (lane < 2) {
    int t = lane;
    int tok = tokbase + t;
    const float* lrow = &Ls[wv * 32 + t * 16];
    float v1 = -1e30f, v2 = -1e30f; int i1 = 0, i2 = 0;
#pragma unroll
    for (int e = 0; e < NE; ++e) {
      float v = lrow[e] + bg[e];
      if (v > v1) { v2 = v1; i2 = i1; v1 = v; i1 = e; }
      else if (v > v2) { v2 = v; i2 = e; }
    }
    float e1 = expf(v2 - v1);
    float den = 1.0f + e1 + 1e-12f;
    float w0 = (1.0f / den) * gamma[i1];
    float w1 = (e1 / den) * gamma[i2];
    pk[tok] = i1 | (i2 << 8);
    wpair[tok] = make_float2(w0, w1);
  }
}

// ---------------- scatter: block-aggregated counting sort into per-bin lists ----------------
__global__ __launch_bounds__(256) void k_scatter(const int* __restrict__ pk,
                                                 const float2* __restrict__ wpair,
                                                 int* __restrict__ cnt,
                                                 int* __restrict__ lists,
                                                 float* __restrict__ wl) {
  __shared__ int lc[32];
  __shared__ int base[32];
  __shared__ int lc2[32];
  int tid = threadIdx.x;
  int tok = blockIdx.x * 256 + tid;
  if (tid < 32) { lc[tid] = 0; lc2[tid] = 0; }
  __syncthreads();
  int p = pk[tok];
  float2 w = wpair[tok];
  int b0 = p & 0xff;
  int b1 = 16 + ((p >> 8) & 0xff);
  atomicAdd(&lc[b0], 1);
  atomicAdd(&lc[b1], 1);
  __syncthreads();
  if (tid < 32 && lc[tid] > 0) base[tid] = atomicAdd(&cnt[tid], lc[tid]);
  __syncthreads();
  int r0 = base[b0] + atomicAdd(&lc2[b0], 1);
  lists[(size_t)b0 * NTOK + r0] = tok;
  wl[(size_t)b0 * NTOK + r0] = w.x;
  int r1 = base[b1] + atomicAdd(&lc2[b1], 1);
  lists[(size_t)b1 * NTOK + r1] = tok;
  wl[(size_t)b1 * NTOK + r1] = w.y;
}

// ---------------- block table: compact (bin, t0) list, one wave ----------------
__global__ void k_btab(const int* __restrict__ cnt, int2* __restrict__ btab,
                       int* __restrict__ nblk) {
  int lane = threadIdx.x;
  int nb = (lane < 32) ? ((cnt[lane] + 63) >> 6) : 0;
  int pfx = nb;
  for (int off = 1; off < 32; off <<= 1) {
    int v = __shfl_up(pfx, off);
    if (lane >= off) pfx += v;
  }
  int start = pfx - nb;
  if (lane < 32) {
    int c = cnt[lane];
    int i = 0;
    for (int t0 = 0; t0 < c; t0 += 64, ++i)
      btab[start + i] = make_int2(lane, t0);
  }
  if (lane == 31) *nblk = pfx;
}

// ---------------- encoder GEMM (R12): 256x256 tile, 8 waves, 2-phase, swizzled LDS ----------------
// R11 post-mortem: 128^2 tile = 64 FLOP/staged-byte; per-CU staging (4 blk x
// 32KB/step) ran at the ~56 B/cy/CU L2 return rate -> staging-bound. 256^2
// doubles intensity (64KB/step, 1 blk/CU, grid=256=1/CU). Same 2-barrier sync.
// Bank-conflict fix per rule #21: linear gload_lds dest + inverse-permuted
// global source chunk (cs = c ^ (row&7)) + XOR on ds_read element addr
// (^ ((row&7)<<3)) -> 16-way conflict becomes <=2-way (free).
// Grid order w = bn*64+bm: each A-panel fetched once.
__global__ __launch_bounds__(512, 1) void k_encgemm(const bf16* __restrict__ A,
                                                    const bf16* __restrict__ W,
                                                    const float* __restrict__ bias,
                                                    bf16* __restrict__ encb) {
  __shared__ bf16 As[256 * 64];
  __shared__ bf16 Bs[256 * 64];
  int tid = threadIdx.x;
  int w = blockIdx.x;            // 256 blocks: w = bn_i*64 + bm_i
  int bm = (w & 63) * 256;
  int bn = (w >> 6) * 256;
  int lane = tid & 63, wv = tid >> 6;
  int wm = (wv >> 2) * 128, wn = (wv & 3) * 64;   // 2M x 4N waves, 128x64 each
  int srow = tid >> 3;           // 0..63
  int sc = tid & 7;              // linear dest chunk
  int cs = sc ^ (srow & 7);      // swizzled source chunk (involution)
  int fr = lane & 15, fk = (lane >> 4) * 8;
  f32x4 acc[8][4] = {};
  for (int k0 = 0; k0 < D_DIM; k0 += 64) {
    __syncthreads();
#pragma unroll
    for (int p = 0; p < 4; ++p) {
      int r = p * 64 + srow;
      gload16(A + (size_t)(bm + r) * D_DIM + k0 + cs * 8, &As[r * 64 + sc * 8]);
    }
#pragma unroll
    for (int p = 0; p < 4; ++p) {
      int r = p * 64 + srow;
      gload16(W + (size_t)(bn + r) * D_DIM + k0 + cs * 8, &Bs[r * 64 + sc * 8]);
    }
    __syncthreads();
#pragma unroll
    for (int kk = 0; kk < 2; ++kk) {
      bf16x8 af[8], bv[4];
#pragma unroll
      for (int m = 0; m < 8; ++m) {
        int row = wm + m * 16 + fr;
        af[m] = *(const bf16x8*)&As[(row * 64 + kk * 32 + fk) ^ ((row & 7) << 3)];
      }
#pragma unroll
      for (int n = 0; n < 4; ++n) {
        int row = wn + n * 16 + fr;
        bv[n] = *(const bf16x8*)&Bs[(row * 64 + kk * 32 + fk) ^ ((row & 7) << 3)];
      }
#pragma unroll
      for (int m = 0; m < 8; ++m)
#pragma unroll
        for (int n = 0; n < 4; ++n)
          acc[m][n] = __builtin_amdgcn_mfma_f32_16x16x32_bf16(af[m], bv[n], acc[m][n], 0, 0, 0);
    }
  }
  int rg = (lane >> 4) * 4;
#pragma unroll
  for (int n = 0; n < 4; ++n) {
    int col = bn + wn + n * 16 + fr;
    float bval = bias[col];
#pragma unroll
    for (int m = 0; m < 8; ++m) {
#pragma unroll
      for (int r = 0; r < 4; ++r) {
        int row = bm + wm + m * 16 + rg + r;
        encb[(size_t)row * D_DIM + col] = (bf16)(acc[m][n][r] + bval);
      }
    }
  }
}

// ---------------- expert kernel (merged slots): S=silu(enc U^T)*coef -> delta = S V^T ----------------
__global__ __launch_bounds__(256) void k_expert(const bf16* __restrict__ encb,
                                                const bf16* __restrict__ Ub,
                                                const bf16* __restrict__ Vb2,
                                                const int* __restrict__ cnt,
                                                const int* __restrict__ lists,
                                                const float* __restrict__ wl,
                                                const int2* __restrict__ btab,
                                                const int* __restrict__ nblk,
                                                bf16* __restrict__ d0,
                                                bf16* __restrict__ d1) {
  int bid = blockIdx.x;
  if (bid >= *nblk) return;
  int2 bt = btab[bid];
  int bin = bt.x, t0 = bt.y;
  int slot = bin >> 4, e = bin & 15;
  int c = cnt[bin];
  int nrows = c - t0; if (nrows > 64) nrows = 64;
  const int* tl = lists + (size_t)bin * NTOK + t0;
  const float* wlp = wl + (size_t)bin * NTOK + t0;

  __shared__ int toks[64];
  __shared__ float coefs[64];
  __shared__ bf16 As[64 * 64];
  __shared__ bf16 Us[64 * 64];
  __shared__ bf16 Ss[64 * 64];

  int tid = threadIdx.x;
  if (tid < 64) {
    int rr = tid < nrows ? tid : nrows - 1;
    toks[tid] = tl[rr];
    coefs[tid] = tid < nrows ? wlp[tid] : 0.0f;
  }
  __syncthreads();

  int lane = tid & 63, wv = tid >> 6;
  int srow = tid >> 3, scol = (tid & 7) * 8;
  int fr = lane & 15, fk = (lane >> 4) * 8;
  size_t tokA0 = (size_t)toks[srow] * D_DIM;
  size_t tokA1 = (size_t)toks[32 + srow] * D_DIM;
  const bf16* Ue = Ub + (size_t)e * RK * D_DIM;
  f32x4 acc1[4] = {};

  for (int k0 = 0; k0 < D_DIM; k0 += 64) {
    __syncthreads();
    gload16(encb + tokA0 + k0 + scol, &As[srow * 64 + scol]);
    gload16(encb + tokA1 + k0 + scol, &As[(32 + srow) * 64 + scol]);
    gload16(Ue + (size_t)srow * D_DIM + k0 + scol, &Us[srow * 64 + scol]);
    gload16(Ue + (size_t)(32 + srow) * D_DIM + k0 + scol, &Us[(32 + srow) * 64 + scol]);
    __syncthreads();
#pragma unroll
    for (int kk = 0; kk < 2; ++kk) {
      bf16x8 af = *(const bf16x8*)&As[(wv * 16 + fr) * 64 + kk * 32 + fk];
#pragma unroll
      for (int n = 0; n < 4; ++n) {
        bf16x8 bv = *(const bf16x8*)&Us[(n * 16 + fr) * 64 + kk * 32 + fk];
        acc1[n] = __builtin_amdgcn_mfma_f32_16x16x32_bf16(af, bv, acc1[n], 0, 0, 0);
      }
    }
  }
  int rg = (lane >> 4) * 4;
#pragma unroll
  for (int n = 0; n < 4; ++n)
#pragma unroll
    for (int r = 0; r < 4; ++r) {
      int row = wv * 16 + rg + r;
      float v = acc1[n][r];
      float s = v / (1.0f + __expf(-v));
      Ss[row * 64 + n * 16 + fr] = (bf16)(s * coefs[row]);
    }
  __syncthreads();
  bf16x8 a2[4][2];
#pragma unroll
  for (int m = 0; m < 4; ++m)
#pragma unroll
    for (int kk = 0; kk < 2; ++kk)
      a2[m][kk] = *(const bf16x8*)&Ss[(m * 16 + fr) * 64 + kk * 32 + fk];

  const bf16* Ve2 = Vb2 + (size_t)e * RK * D_DIM;
  bf16* dst = slot ? d1 : d0;
  int rb0 = lane >> 4;
  int colbase = wv * 256;
  for (int nj = 0; nj < 16; ++nj) {
    int dcol = colbase + nj * 16 + fr;
    bf16x8 b0 = *(const bf16x8*)&Ve2[((size_t)rb0 * D_DIM + dcol) * 8];
    bf16x8 b1 = *(const bf16x8*)&Ve2[((size_t)(rb0 + 4) * D_DIM + dcol) * 8];
#pragma unroll
    for (int m = 0; m < 4; ++m) {
      f32x4 a = {};
      a = __builtin_amdgcn_mfma_f32_16x16x32_bf16(a2[m][0], b0, a, 0, 0, 0);
      a = __builtin_amdgcn_mfma_f32_16x16x32_bf16(a2[m][1], b1, a, 0, 0, 0);
#pragma unroll
      for (int r = 0; r < 4; ++r) {
        int row = m * 16 + rg + r;
        if (row < nrows) {
          dst[(size_t)toks[row] * D_DIM + dcol] = (bf16)a[r];
        }
      }
    }
  }
}

// ---------------- final: out = encb + d0 + d1 (pure streams, no RMW) ----------------
__global__ __launch_bounds__(256) void k_final(float* __restrict__ out,
                                               const bf16* __restrict__ encb,
                                               const bf16* __restrict__ d0,
                                               const bf16* __restrict__ d1) {
  size_t i = ((size_t)blockIdx.x * 256 + threadIdx.x) * 8;
  bf16x8 e = *(const bf16x8*)(encb + i);
  bf16x8 a = *(const bf16x8*)(d0 + i);
  bf16x8 b = *(const bf16x8*)(d1 + i);
  float4 o0, o1;
  o0.x = (float)e[0] + (float)a[0] + (float)b[0];
  o0.y = (float)e[1] + (float)a[1] + (float)b[1];
  o0.z = (float)e[2] + (float)a[2] + (float)b[2];
  o0.w = (float)e[3] + (float)a[3] + (float)b[3];
  o1.x = (float)e[4] + (float)a[4] + (float)b[4];
  o1.y = (float)e[5] + (float)a[5] + (float)b[5];
  o1.z = (float)e[6] + (float)a[6] + (float)b[6];
  o1.w = (float)e[7] + (float)a[7] + (float)b[7];
  *(float4*)(out + i) = o0;
  *(float4*)(out + i + 4) = o1;
}

extern "C" void kernel_launch(void* const* d_in, const int* in_sizes, int n_in,
                              void* d_out, int out_size, void* d_ws, size_t ws_size,
                              hipStream_t stream) {
  const float* x   = (const float*)d_in[0];
  const float* We  = (const float*)d_in[1];
  const float* be  = (const float*)d_in[2];
  const float* Wg  = (const float*)d_in[3];
  const float* U   = (const float*)d_in[4];
  const float* V   = (const float*)d_in[5];
  const float* gam = (const float*)d_in[6];
  float* out = (float*)d_out;
  char* ws = (char*)d_ws;

  int*    cnt  = (int*)(ws + 0);                       // 128 B   (zeroed)
  float*  Gt2  = (float*)(ws + 256);                   // 64 KiB  (zeroed), [d/4][e][4]
  float*  bg   = (float*)(ws + 66048);                 // 64 B
  int2*   btab = (int2*)(ws + 66176);                  // 4.25 KiB
  int*    nblk = (int*)(ws + 70656);                   // 4 B
  bf16*   xb   = (bf16*)(ws + 131072);                 // 32 MiB (aliased: d0 after encgemm)
  bf16*   d0   = (bf16*)(ws + 131072);
  bf16*   encb = (bf16*)(ws + 131072 + 33554432);      // 32 MiB
  char*   base = ws + 131072 + 2 * 33554432;
  bf16*   Wb   = (bf16*)(base);                        // 2 MiB
  bf16*   Ubf  = (bf16*)(base + 2097152);              // 2 MiB
  bf16*   Vb2  = (bf16*)(base + 2 * 2097152);          // 2 MiB  [e][r/8][d][8]
  int*    lists= (int*)(base + 3 * 2097152);           // 2 MiB
  float*  wl   = (float*)(base + 4 * 2097152);         // 2 MiB
  int*    pk   = (int*)(base + 5 * 2097152);           // 64 KiB
  float2* wpr  = (float2*)(base + 5 * 2097152 + 131072); // 128 KiB
  bf16*   d1   = (bf16*)(base + 5 * 2097152 + 131072 + 131072 + 131072); // 32 MiB

  hipMemsetAsync(ws, 0, 66048, stream);

  k_cast<<<1024, 256, 0, stream>>>(We, Wb, 1048576 / 4);
  k_cast<<<1024, 256, 0, stream>>>(U, Ubf, 1048576 / 4);
  k_castv<<<512, 256, 0, stream>>>(V, Vb2);

  dim3 gg(4, 16, 8);
  k_gmat<<<gg, 256, 0, stream>>>(Wg, We, Gt2);
  k_bgate<<<16, 256, 0, stream>>>(Wg, be, bg);

  k_gatecast<<<2048, 256, 0, stream>>>(x, Gt2, bg, gam, xb, pk, wpr);
  k_scatter<<<64, 256, 0, stream>>>(pk, wpr, cnt, lists, wl);
  k_btab<<<1, 64, 0, stream>>>(cnt, btab, nblk);

  k_encgemm<<<256, 512, 0, stream>>>(xb, Wb, be, encb);

  k_expert<<<544, 256, 0, stream>>>(encb, Ubf, Vb2, cnt, lists, wl, btab, nblk, d0, d1);
  k_final<<<8192, 256, 0, stream>>>(out, encb, d0, d1);
}